// Round 3
// baseline (1504.212 us; speedup 1.0000x reference)
//
#include <hip/hip_runtime.h>

typedef unsigned short u16;
typedef __bf16 bf16x8 __attribute__((ext_vector_type(8)));
typedef float f32x4 __attribute__((ext_vector_type(4)));

constexpr int Bq  = 4;
constexpr int Sq  = 2048;
constexpr int Hq  = 1024;
constexpr int NHq = 16;
constexpr int HDq = 64;
constexpr int CCH = 16;    // chunks
constexpr int LCH = 128;   // chunk length

// workspace layout (bytes), total 212,860,928
constexpr size_t OFF_WB = 0;             // W bf16: 5*1M*2 = 10,485,760
constexpr size_t OFF_XB = 10485760;      // 16,777,216: x-bf16 -> Qc (scan) -> y-bf16 (epilogue)
constexpr size_t OFF_Q  = 27262976;      // q fp32: 33,554,432
constexpr size_t OFF_K  = 60817408;
constexpr size_t OFF_V  = 94371840;
constexpr size_t OFF_G  = 127926272;
constexpr size_t OFF_AL = 161480704;     // alpha: 524,288
constexpr size_t OFF_BE = 162004992;
constexpr size_t OFF_P  = 162529280;     // Wab bf16 (64 KB, 32 rows) during GEMM -> chunk P (16 MB) during scan
constexpr size_t OFF_O  = 179306496;     // of fp32: 33,554,432 (end 212,860,928)

__device__ __forceinline__ u16 f2bf(float f) {
  unsigned u = __float_as_uint(f);
  u += 0x7fffu + ((u >> 16) & 1u);
  return (u16)(u >> 16);
}
__device__ __forceinline__ float sigmoidf_(float x) { return 1.f / (1.f + __expf(-x)); }

__device__ __forceinline__ void async16(const void* g, void* l) {
  __builtin_amdgcn_global_load_lds((const __attribute__((address_space(1))) void*)g,
                                   (__attribute__((address_space(3))) void*)l, 16, 0, 0);
}

// ---------------- converts ----------------
__global__ __launch_bounds__(256) void cvt_x_kernel(const float* __restrict__ in, u16* __restrict__ outp) {
  const size_t i = ((size_t)blockIdx.x * 256 + threadIdx.x) * 4;
  float4 f = *(const float4*)(in + i);
  ushort4 u; u.x = f2bf(f.x); u.y = f2bf(f.y); u.z = f2bf(f.z); u.w = f2bf(f.w);
  *(ushort4*)(outp + i) = u;
}

__global__ __launch_bounds__(256) void cvt_w_kernel(const float* __restrict__ w0, const float* __restrict__ w1,
    const float* __restrict__ w2, const float* __restrict__ w3, const float* __restrict__ w4,
    u16* __restrict__ outp) {
  const int z = blockIdx.z;
  const float* src = (z == 0) ? w0 : (z == 1) ? w1 : (z == 2) ? w2 : (z == 3) ? w3 : w4;
  const size_t i = ((size_t)blockIdx.x * 256 + threadIdx.x) * 4;
  float4 f = *(const float4*)(src + i);
  ushort4 u; u.x = f2bf(f.x); u.y = f2bf(f.y); u.z = f2bf(f.z); u.w = f2bf(f.w);
  *(ushort4*)(outp + (size_t)z * (1024 * 1024) + i) = u;
}

// Wab: 32x1024 bf16; rows 0..15 = Wa, 16..31 = Wb
__global__ __launch_bounds__(256) void cvt_ab_kernel(const float* __restrict__ Wa, const float* __restrict__ Wb,
    u16* __restrict__ outp) {
  const size_t i = ((size_t)blockIdx.x * 256 + threadIdx.x) * 4;
  const int row = (int)(i >> 10);
  const float* src = (row < 16) ? (Wa + i) : (Wb + i - 16 * 1024);
  float4 f = *(const float4*)src;
  ushort4 u; u.x = f2bf(f.x); u.y = f2bf(f.y); u.z = f2bf(f.z); u.w = f2bf(f.w);
  *(ushort4*)(outp + i) = u;
}

// ---------------- alpha/beta GEMM: 8192x32 = x @ [Wa;Wb]^T, tiny, MFMA direct-from-global ----------------
// 64 blocks x 256 thr; wave wv owns 32 rows; acc 2mi x 2ni (ni0 -> alpha cols, ni1 -> beta cols).
__global__ __launch_bounds__(256) void ab_gemm(const u16* __restrict__ A, const u16* __restrict__ Wab,
    float* __restrict__ al, float* __restrict__ be, const float* __restrict__ ba, const float* __restrict__ bb) {
  const int tid = threadIdx.x, wv = tid >> 6, lane = tid & 63;
  const int l15 = lane & 15, qd = lane >> 4;
  const int m0 = blockIdx.x * 128 + wv * 32;
  const u16* gA = A + (size_t)m0 * 1024 + qd * 8;
  const u16* gB = Wab + (size_t)l15 * 1024 + qd * 8;
  f32x4 acc[2][2] = {};
#pragma unroll 4
  for (int kt = 0; kt < 1024; kt += 32) {
    bf16x8 a0 = *(const bf16x8*)(gA + (size_t)l15 * 1024 + kt);
    bf16x8 a1 = *(const bf16x8*)(gA + (size_t)(16 + l15) * 1024 + kt);
    bf16x8 b0 = *(const bf16x8*)(gB + kt);
    bf16x8 b1 = *(const bf16x8*)(gB + 16 * 1024 + kt);
    acc[0][0] = __builtin_amdgcn_mfma_f32_16x16x32_bf16(a0, b0, acc[0][0], 0, 0, 0);
    acc[0][1] = __builtin_amdgcn_mfma_f32_16x16x32_bf16(a0, b1, acc[0][1], 0, 0, 0);
    acc[1][0] = __builtin_amdgcn_mfma_f32_16x16x32_bf16(a1, b0, acc[1][0], 0, 0, 0);
    acc[1][1] = __builtin_amdgcn_mfma_f32_16x16x32_bf16(a1, b1, acc[1][1], 0, 0, 0);
  }
  const float bav = ba[l15], bbv = bb[l15];
#pragma unroll
  for (int mi = 0; mi < 2; ++mi) {
    const int row = m0 + mi * 16 + qd * 4;
#pragma unroll
    for (int r = 0; r < 4; ++r) {
      al[(size_t)(row + r) * 16 + l15] = sigmoidf_(acc[mi][0][r] + bav);
      be[(size_t)(row + r) * 16 + l15] = sigmoidf_(acc[mi][1][r] + bbv);
    }
  }
}

// ============ 256x256 8-phase bf16 MFMA GEMM (T1+T2+T3+T4+T5) with fused epilogues ============
// 512 thr = 8 waves (2M x 4N); per-wave C = 128x64; BK=64.
// LDS = 2 bufs x {A,B} x 256x64 bf16 = 128 KiB -> 1 block/CU, 2 waves/SIMD.
// T1: bijective XCD swizzle; jobs grouped so each XCD's chunk shares B-panels (same z,ny).
// T2 swizzle: 16B slot s_phys = s_log ^ (row&7); applied on the gload_lds SOURCE (linear dest)
//   and on the ds_read side -> conflict-free ds_read_b128.
// T3/T4 staging: tile t: ph0 A-h0(t+1), ph1 A-h1(t+1), ph2 B-h0(t+2), ph3 B-h1(t+2);
//   boundary s_waitcnt vmcnt(4) keeps 2 half-tiles in flight. T5: setprio around MFMA clusters.

__device__ __forceinline__ void lda4(bf16x8 af[4][2], const u16* LA, int wr, int mh, int l15, int qd, int l7) {
#pragma unroll
  for (int i = 0; i < 4; ++i)
#pragma unroll
    for (int kk = 0; kk < 2; ++kk)
      af[i][kk] = *(const bf16x8*)(LA + (wr * 128 + mh * 64 + i * 16 + l15) * 64 + (((kk * 4 + qd) ^ l7) * 8));
}
__device__ __forceinline__ void ldb2(bf16x8 bf[2][2], const u16* LB, int wc, int nh, int l15, int qd, int l7) {
#pragma unroll
  for (int j = 0; j < 2; ++j)
#pragma unroll
    for (int kk = 0; kk < 2; ++kk)
      bf[j][kk] = *(const bf16x8*)(LB + (wc * 64 + nh * 32 + j * 16 + l15) * 64 + (((kk * 4 + qd) ^ l7) * 8));
}
__device__ __forceinline__ void mm16(f32x4 acc[8][4], const bf16x8 af[4][2], const bf16x8 bf[2][2], int mh, int nh) {
#pragma unroll
  for (int i = 0; i < 4; ++i)
#pragma unroll
    for (int j = 0; j < 2; ++j) {
      f32x4 c = acc[mh * 4 + i][nh * 2 + j];
      c = __builtin_amdgcn_mfma_f32_16x16x32_bf16(af[i][0], bf[j][0], c, 0, 0, 0);
      c = __builtin_amdgcn_mfma_f32_16x16x32_bf16(af[i][1], bf[j][1], c, 0, 0, 0);
      acc[mh * 4 + i][nh * 2 + j] = c;
    }
}
// stage one 128x64 half-tile (16 KB) = 2 x global_load_lds(16B) per thread; linear LDS dest,
// inverse-swizzled global source.
__device__ __forceinline__ void stageH(u16* LD, int bufp, int mat, int h, const u16* gRow0, int kElem,
                                       int rr, int sl8, int wv) {
  const u16* s0 = gRow0 + (size_t)(h * 128 + rr) * 1024 + kElem + sl8;
  u16* d = LD + bufp * 32768 + mat * 16384 + h * 8192 + wv * 512;
  async16(s0, d);
  async16(s0 + (size_t)(64 * 1024), d + 4096);
}

template<int S1, int S2, int VM>
__device__ __forceinline__ void tile16(u16* LD, int bp, int kt,
    const u16* gA, const u16* gB, f32x4 acc[8][4], bf16x8 af[4][2], bf16x8 bf0[2][2], bf16x8 bf1[2][2],
    int wr, int wc, int l15, int qd, int l7, int rr, int sl8, int wv) {
  const u16* LA = LD + bp * 32768;
  const u16* LB = LA + 16384;
  // ---- ph0: quadrant (mh0, nh0); stage A-h0(t+1)
  lda4(af, LA, wr, 0, l15, qd, l7);
  ldb2(bf0, LB, wc, 0, l15, qd, l7);
  if (S1) stageH(LD, bp ^ 1, 0, 0, gA, (kt + 1) * 64, rr, sl8, wv);
  __builtin_amdgcn_s_barrier();
  asm volatile("s_waitcnt lgkmcnt(0)" ::: "memory");
  __builtin_amdgcn_sched_barrier(0);
  __builtin_amdgcn_s_setprio(1);
  mm16(acc, af, bf0, 0, 0);
  __builtin_amdgcn_s_setprio(0);
  __builtin_amdgcn_s_barrier();
  // ---- ph1: (mh0, nh1); stage A-h1(t+1)
  ldb2(bf1, LB, wc, 1, l15, qd, l7);
  if (S1) stageH(LD, bp ^ 1, 0, 1, gA, (kt + 1) * 64, rr, sl8, wv);
  __builtin_amdgcn_s_barrier();
  asm volatile("s_waitcnt lgkmcnt(0)" ::: "memory");
  __builtin_amdgcn_sched_barrier(0);
  __builtin_amdgcn_s_setprio(1);
  mm16(acc, af, bf1, 0, 1);
  __builtin_amdgcn_s_setprio(0);
  __builtin_amdgcn_s_barrier();
  // ---- ph2: (mh1, nh0); stage B-h0(t+2)
  lda4(af, LA, wr, 1, l15, qd, l7);
  if (S2) stageH(LD, bp, 1, 0, gB, (kt + 2) * 64, rr, sl8, wv);
  __builtin_amdgcn_s_barrier();
  asm volatile("s_waitcnt lgkmcnt(0)" ::: "memory");
  __builtin_amdgcn_sched_barrier(0);
  __builtin_amdgcn_s_setprio(1);
  mm16(acc, af, bf0, 1, 0);
  __builtin_amdgcn_s_setprio(0);
  __builtin_amdgcn_s_barrier();
  // ---- ph3: (mh1, nh1); stage B-h1(t+2); boundary counted-vmcnt then barrier
  if (S2) stageH(LD, bp, 1, 1, gB, (kt + 2) * 64, rr, sl8, wv);
  __builtin_amdgcn_s_barrier();
  __builtin_amdgcn_sched_barrier(0);
  __builtin_amdgcn_s_setprio(1);
  mm16(acc, af, bf1, 1, 1);
  __builtin_amdgcn_s_setprio(0);
  if (VM == 4) asm volatile("s_waitcnt vmcnt(4)" ::: "memory");
  else if (VM == 0) asm volatile("s_waitcnt vmcnt(0)" ::: "memory");
  __builtin_amdgcn_s_barrier();
}

// mode 0: plain store to Cq (final out-proj), grid 128.
// mode 1: z = q,k,v,g with fused l2norm/l2norm/silu/plain epilogues, grid 512.
__global__ __launch_bounds__(512, 2) void gemm256(const u16* __restrict__ A, const u16* __restrict__ Wall,
    float* __restrict__ Cq, float* __restrict__ Ck, float* __restrict__ Cv, float* __restrict__ Cg,
    int mode) {
  __shared__ __align__(16) u16 Lds[65536];   // 128 KiB: [buf][A|B][256][64] bf16
  u16* LD = &Lds[0];
  const int tid = threadIdx.x;
  const int wv = tid >> 6, lane = tid & 63;
  const int l15 = lane & 15, qd = lane >> 4, l7 = l15 & 7;
  const int wr = wv >> 2, wc = wv & 3;
  const int rr = tid >> 3, sl8 = ((tid & 7) ^ (rr & 7)) * 8;

  // T1 bijective XCD swizzle (grid % 8 == 0): each XCD gets a contiguous job chunk;
  // jobs ordered (z,ny major, mx minor) so a chunk shares B-panels.
  int mx, ny, z;
  const u16* Wm;
  if (mode == 0) {
    const int job = ((blockIdx.x & 7) << 4) + (blockIdx.x >> 3);   // 128 jobs
    mx = job & 31; ny = job >> 5; z = 0; Wm = Wall;
  } else {
    const int job = ((blockIdx.x & 7) << 6) + (blockIdx.x >> 3);   // 512 jobs
    mx = job & 31; ny = (job >> 5) & 3; z = job >> 7;
    Wm = Wall + (size_t)z * (1024 * 1024);
  }
  const int m0 = mx * 256, n0 = ny * 256;
  const u16* gA = A + (size_t)m0 * 1024;
  const u16* gB = Wm + (size_t)n0 * 1024;

  f32x4 acc[8][4] = {};
  bf16x8 af[4][2], bf0[2][2], bf1[2][2];

  // prologue: tile0 all 4 halves -> buf0; tile1 B halves -> buf1; wait tile0 landed (4 loads in flight)
  stageH(LD, 0, 0, 0, gA, 0,  rr, sl8, wv);
  stageH(LD, 0, 0, 1, gA, 0,  rr, sl8, wv);
  stageH(LD, 0, 1, 0, gB, 0,  rr, sl8, wv);
  stageH(LD, 0, 1, 1, gB, 0,  rr, sl8, wv);
  stageH(LD, 1, 1, 0, gB, 64, rr, sl8, wv);
  stageH(LD, 1, 1, 1, gB, 64, rr, sl8, wv);
  asm volatile("s_waitcnt vmcnt(4)" ::: "memory");
  __builtin_amdgcn_s_barrier();

  // 16 K-tiles (K=1024, BK=64); 2 tiles per iter so buffer parity is compile-time
#pragma unroll 1
  for (int t2 = 0; t2 < 7; ++t2) {
    tile16<1, 1, 4>(LD, 0, 2 * t2,     gA, gB, acc, af, bf0, bf1, wr, wc, l15, qd, l7, rr, sl8, wv);
    tile16<1, 1, 4>(LD, 1, 2 * t2 + 1, gA, gB, acc, af, bf0, bf1, wr, wc, l15, qd, l7, rr, sl8, wv);
  }
  tile16<1, 0, 0>(LD, 0, 14, gA, gB, acc, af, bf0, bf1, wr, wc, l15, qd, l7, rr, sl8, wv);
  tile16<0, 0, -1>(LD, 1, 15, gA, gB, acc, af, bf0, bf1, wr, wc, l15, qd, l7, rr, sl8, wv);

  // ---- epilogues ---- C/D layout per 16x16 frag: col = l15, row = qd*4 + r
  if (mode == 1 && z <= 1) {
    // l2norm over the head dim: wave's 64 cols = exactly one head
#pragma unroll
    for (int mi = 0; mi < 8; ++mi)
#pragma unroll
      for (int r = 0; r < 4; ++r) {
        float ss = acc[mi][0][r] * acc[mi][0][r] + acc[mi][1][r] * acc[mi][1][r]
                 + acc[mi][2][r] * acc[mi][2][r] + acc[mi][3][r] * acc[mi][3][r];
        ss += __shfl_xor(ss, 1); ss += __shfl_xor(ss, 2);
        ss += __shfl_xor(ss, 4); ss += __shfl_xor(ss, 8);
        const float rn = 1.f / fmaxf(sqrtf(ss), 1e-12f);
        acc[mi][0][r] *= rn; acc[mi][1][r] *= rn; acc[mi][2][r] *= rn; acc[mi][3][r] *= rn;
      }
  } else if (mode == 1 && z == 2) {
#pragma unroll
    for (int mi = 0; mi < 8; ++mi)
#pragma unroll
      for (int ni = 0; ni < 4; ++ni)
#pragma unroll
        for (int r = 0; r < 4; ++r)
          acc[mi][ni][r] = acc[mi][ni][r] * sigmoidf_(acc[mi][ni][r]);
  }
  float* C = (mode == 0) ? Cq : ((z == 0) ? Cq : (z == 1) ? Ck : (z == 2) ? Cv : Cg);
#pragma unroll
  for (int mi = 0; mi < 8; ++mi) {
    const int row = m0 + wr * 128 + mi * 16 + qd * 4;
#pragma unroll
    for (int ni = 0; ni < 4; ++ni) {
      const int col = n0 + wc * 64 + ni * 16 + l15;
#pragma unroll
      for (int r = 0; r < 4; ++r)
        C[(size_t)(row + r) * 1024 + col] = acc[mi][ni][r];
    }
  }
}

// ================= chunked scan: 1 chunk/block, 4 row-split waves (4 blocks/CU) =================
// Block = (bh, chunk). Wave wv owns rows wv*16..+15; lane: rg=lane>>3 (2-row), cg=lane&7 (8-col).
// 16-token tiles staged to LDS (double-buffered) via global_load_lds, shared by all 4 waves.
// Inner loop SOFTWARE-PIPELINED across tokens: token t+1's LDS loads issue under token t's VALU.
struct ScanLds1 { float kb[2][16 * 64]; float vb[2][16 * 64]; float ab[2][32]; };
struct ScanLds2 { float kb[2][16 * 64]; float qb[2][16 * 64]; float vb[2][16 * 64]; float ab[2][32]; };

// pass 1: compose affine maps over the chunk (Pr/Qr, 2x8 tile per lane)
__global__ __launch_bounds__(256, 4) void scan_p1(const float* __restrict__ k, const float* __restrict__ v,
    const float* __restrict__ al, const float* __restrict__ be,
    float* __restrict__ P, float* __restrict__ Q) {
  __shared__ ScanLds1 L;
  const int tid = threadIdx.x, wv = tid >> 6, lane = tid & 63;
  const int bh = blockIdx.x >> 4, c = blockIdx.x & 15;
  const int b = bh >> 4, h = bh & 15;
  const int rg = lane >> 3, cg = lane & 7;
  const int r0 = wv * 16 + rg * 2, c8 = cg * 8;
  const size_t base0 = ((size_t)(b * Sq + c * LCH)) * 1024 + h * 64;
  const size_t ab0   = ((size_t)(b * Sq + c * LCH)) * 16 + h;
  const int tokw = lane >> 4, seg = lane & 15;
  auto stage = [&](int tile, int bi) {
    #pragma unroll
    for (int j = 0; j < 2; ++j) {        // 8 jobs: (arr{k,v}, quarter)
      const int job = wv * 2 + j;
      const int arr = job >> 2, i = job & 3;
      const float* src = arr ? v : k;
      float* dst = arr ? &L.vb[bi][i * 256] : &L.kb[bi][i * 256];
      async16(src + base0 + (size_t)(tile * 16 + i * 4 + tokw) * 1024 + seg * 4, dst);
    }
    if (wv == 0 && lane < 32) {          // a/b: 32 values, one lane each
      const int w16 = lane >> 4, tt = lane & 15;
      const float* s = w16 ? be : al;
      L.ab[bi][w16 * 16 + tt] = s[ab0 + (size_t)(tile * 16 + tt) * 16];
    }
  };
  float Pr[16], Qr[16];
  #pragma unroll
  for (int i = 0; i < 16; ++i) { Pr[i] = 1.f; Qr[i] = 0.f; }
  stage(0, 0);
  for (int tile = 0; tile < 8; ++tile) {
    __syncthreads();
    if (tile < 7) stage(tile + 1, (tile + 1) & 1);
    const int bi = tile & 1;
    const float* kbp = L.kb[bi];
    const float* vbp = L.vb[bi];
    const float* abp = L.ab[bi];
    float4 kc0 = *(const float4*)(kbp + c8);
    float4 kc1 = *(const float4*)(kbp + c8 + 4);
    float2 krp = *(const float2*)(kbp + r0);
    float2 vrp = *(const float2*)(vbp + r0);
    float  ap = abp[0], btp = abp[16];
    #pragma unroll
    for (int tt = 0; tt < 16; ++tt) {
      float4 nk0, nk1; float2 nkr, nvr; float na, nbt;
      if (tt < 15) {   // prefetch token tt+1 under token tt's compute
        const float* kq = kbp + (tt + 1) * 64;
        nk0 = *(const float4*)(kq + c8);
        nk1 = *(const float4*)(kq + c8 + 4);
        nkr = *(const float2*)(kq + r0);
        nvr = *(const float2*)(vbp + (tt + 1) * 64 + r0);
        na  = abp[tt + 1]; nbt = abp[16 + tt + 1];
      }
      const float kcv[8] = {kc0.x, kc0.y, kc0.z, kc0.w, kc1.x, kc1.y, kc1.z, kc1.w};
      const float abt = ap * btp;
      const float c1a = abt * krp.x, c1b = abt * krp.y;
      const float c2a = btp * vrp.x, c2b = btp * vrp.y;
      #pragma unroll
      for (int j = 0; j < 8; ++j) {
        const float A0 = fmaf(-c1a, kcv[j], ap);
        Qr[j] = fmaf(A0, Qr[j], c2a * kcv[j]);
        Pr[j] *= A0;
        const float A1 = fmaf(-c1b, kcv[j], ap);
        Qr[8 + j] = fmaf(A1, Qr[8 + j], c2b * kcv[j]);
        Pr[8 + j] *= A1;
      }
      if (tt < 15) { kc0 = nk0; kc1 = nk1; krp = nkr; vrp = nvr; ap = na; btp = nbt; }
    }
  }
  const size_t pbase = ((size_t)bh * CCH + c) * 4096 + (size_t)c8;
  #pragma unroll
  for (int i = 0; i < 2; ++i) {
    const size_t pi = pbase + (size_t)(r0 + i) * 64;
    *(float4*)(P + pi)     = make_float4(Pr[i*8],   Pr[i*8+1], Pr[i*8+2], Pr[i*8+3]);
    *(float4*)(P + pi + 4) = make_float4(Pr[i*8+4], Pr[i*8+5], Pr[i*8+6], Pr[i*8+7]);
    *(float4*)(Q + pi)     = make_float4(Qr[i*8],   Qr[i*8+1], Qr[i*8+2], Qr[i*8+3]);
    *(float4*)(Q + pi + 4) = make_float4(Qr[i*8+4], Qr[i*8+5], Qr[i*8+6], Qr[i*8+7]);
  }
}

// pass 2: sequential combine over chunks; writes chunk-initial state over P
__global__ __launch_bounds__(256) void scan_comb(float* __restrict__ P, const float* __restrict__ Q) {
  const int g = blockIdx.x * 256 + threadIdx.x;  // 0..262143
  const int elem = g & 4095;
  const int bh = g >> 12;
  float s = 0.f;
  #pragma unroll
  for (int c = 0; c < CCH; ++c) {
    const size_t idx = ((size_t)bh * CCH + c) * 4096 + elem;
    const float p = P[idx], qq = Q[idx];
    P[idx] = s;
    s = fmaf(p, s, qq);
  }
}

// pass 3: re-iterate chunk from s_init, emit outputs
__global__ __launch_bounds__(256, 4) void scan_p2(const float* __restrict__ q, const float* __restrict__ k,
    const float* __restrict__ v, const float* __restrict__ al, const float* __restrict__ be,
    const float* __restrict__ Pini, float* __restrict__ o) {
  __shared__ ScanLds2 L;
  const int tid = threadIdx.x, wv = tid >> 6, lane = tid & 63;
  const int bh = blockIdx.x >> 4, c = blockIdx.x & 15;
  const int b = bh >> 4, h = bh & 15;
  const int rg = lane >> 3, cg = lane & 7;
  const int r0 = wv * 16 + rg * 2, c8 = cg * 8;
  const size_t base0 = ((size_t)(b * Sq + c * LCH)) * 1024 + h * 64;
  const size_t ab0   = ((size_t)(b * Sq + c * LCH)) * 16 + h;
  const size_t pbase = ((size_t)bh * CCH + c) * 4096 + (size_t)c8;
  const int tokw = lane >> 4, seg = lane & 15;
  auto stage = [&](int tile, int bi) {
    #pragma unroll
    for (int j = 0; j < 3; ++j) {        // 12 jobs: (arr{k,q,v}, quarter)
      const int job = wv * 3 + j;
      const int arr = job >> 2, i = job & 3;
      const float* src = (arr == 0) ? k : (arr == 1) ? q : v;
      float* dst = (arr == 0) ? &L.kb[bi][i * 256] : (arr == 1) ? &L.qb[bi][i * 256]
                                                                : &L.vb[bi][i * 256];
      async16(src + base0 + (size_t)(tile * 16 + i * 4 + tokw) * 1024 + seg * 4, dst);
    }
    if (wv == 0 && lane < 32) {
      const int w16 = lane >> 4, tt = lane & 15;
      const float* s = w16 ? be : al;
      L.ab[bi][w16 * 16 + tt] = s[ab0 + (size_t)(tile * 16 + tt) * 16];
    }
  };
  float st[16];
  #pragma unroll
  for (int i = 0; i < 2; ++i) {
    float4 s0 = *(const float4*)(Pini + pbase + (size_t)(r0 + i) * 64);
    float4 s1 = *(const float4*)(Pini + pbase + (size_t)(r0 + i) * 64 + 4);
    st[i*8]   = s0.x; st[i*8+1] = s0.y; st[i*8+2] = s0.z; st[i*8+3] = s0.w;
    st[i*8+4] = s1.x; st[i*8+5] = s1.y; st[i*8+6] = s1.z; st[i*8+7] = s1.w;
  }
  stage(0, 0);
  const bool hi4 = (cg & 4);
  const int rowIdx = r0 + (cg >> 2);
  const bool doStore = ((cg & 3) == 0);
  for (int tile = 0; tile < 8; ++tile) {
    __syncthreads();
    if (tile < 7) stage(tile + 1, (tile + 1) & 1);
    const int bi = tile & 1;
    const float* kbp = L.kb[bi];
    const float* qbp = L.qb[bi];
    const float* vbp = L.vb[bi];
    const float* abp = L.ab[bi];
    float4 kc0 = *(const float4*)(kbp + c8);
    float4 kc1 = *(const float4*)(kbp + c8 + 4);
    float4 qc0 = *(const float4*)(qbp + c8);
    float4 qc1 = *(const float4*)(qbp + c8 + 4);
    float2 krp = *(const float2*)(kbp + r0);
    float2 vrp = *(const float2*)(vbp + r0);
    float  ap = abp[0], btp = abp[16];
    #pragma unroll
    for (int tt = 0; tt < 16; ++tt) {
      float4 nk0, nk1, nq0, nq1; float2 nkr, nvr; float na, nbt;
      if (tt < 15) {   // prefetch token tt+1 under token tt's compute
        const float* kq = kbp + (tt + 1) * 64;
        const float* qq = qbp + (tt + 1) * 64;
        nk0 = *(const float4*)(kq + c8);
        nk1 = *(const float4*)(kq + c8 + 4);
        nq0 = *(const float4*)(qq + c8);
        nq1 = *(const float4*)(qq + c8 + 4);
        nkr = *(const float2*)(kq + r0);
        nvr = *(const float2*)(vbp + (tt + 1) * 64 + r0);
        na  = abp[tt + 1]; nbt = abp[16 + tt + 1];
      }
      const int t = tile * 16 + tt;
      const float kcv[8] = {kc0.x, kc0.y, kc0.z, kc0.w, kc1.x, kc1.y, kc1.z, kc1.w};
      const float qcv[8] = {qc0.x, qc0.y, qc0.z, qc0.w, qc1.x, qc1.y, qc1.z, qc1.w};
      const float abt = ap * btp;
      const float c1a = abt * krp.x, c1b = abt * krp.y;
      const float c2a = btp * vrp.x, c2b = btp * vrp.y;
      float p0 = 0.f, p1v = 0.f;
      #pragma unroll
      for (int j = 0; j < 8; ++j) {
        const float A0 = fmaf(-c1a, kcv[j], ap);
        st[j] = fmaf(A0, st[j], c2a * kcv[j]);
        p0 = fmaf(st[j], qcv[j], p0);
        const float A1 = fmaf(-c1b, kcv[j], ap);
        st[8 + j] = fmaf(A1, st[8 + j], c2b * kcv[j]);
        p1v = fmaf(st[8 + j], qcv[j], p1v);
      }
      // reduce over the 8 col-lanes: keep-one/send-one split at xor4, then xor2/xor1.
      float my    = hi4 ? p1v : p0;
      float other = hi4 ? p0 : p1v;
      my += __shfl_xor(other, 4);
      my += __shfl_xor(my, 2);
      my += __shfl_xor(my, 1);
      if (doStore) o[base0 + (size_t)t * 1024 + rowIdx] = my;
      if (tt < 15) { kc0 = nk0; kc1 = nk1; qc0 = nq0; qc1 = nq1; krp = nkr; vrp = nvr; ap = na; btp = nbt; }
    }
  }
}

// ---------------- LayerNorm + silu-gate, write bf16 ----------------
__global__ __launch_bounds__(256) void ln_gate_kernel(const float* __restrict__ o, const float* __restrict__ g,
    const float* __restrict__ ln_g, const float* __restrict__ ln_b, u16* __restrict__ y) {
  const int t = blockIdx.x, tid = threadIdx.x;
  const size_t row = (size_t)t * 1024;
  float4 xv = *(const float4*)(o + row + tid * 4);
  float s  = xv.x + xv.y + xv.z + xv.w;
  float s2 = xv.x * xv.x + xv.y * xv.y + xv.z * xv.z + xv.w * xv.w;
  #pragma unroll
  for (int m = 1; m < 64; m <<= 1) { s += __shfl_xor(s, m); s2 += __shfl_xor(s2, m); }
  __shared__ float red[8];
  const int w = tid >> 6, lane = tid & 63;
  if (lane == 0) { red[w] = s; red[4 + w] = s2; }
  __syncthreads();
  s  = red[0] + red[1] + red[2] + red[3];
  s2 = red[4] + red[5] + red[6] + red[7];
  const float mu = s * (1.f / 1024.f);
  const float var = s2 * (1.f / 1024.f) - mu * mu;
  const float rstd = rsqrtf(var + 1e-5f);
  float4 gv = *(const float4*)(g + row + tid * 4);
  float4 lg = *(const float4*)(ln_g + tid * 4);
  float4 lb = *(const float4*)(ln_b + tid * 4);
  ushort4 u;
  u.x = f2bf(((xv.x - mu) * rstd * lg.x + lb.x) * (gv.x * sigmoidf_(gv.x)));
  u.y = f2bf(((xv.y - mu) * rstd * lg.y + lb.y) * (gv.y * sigmoidf_(gv.y)));
  u.z = f2bf(((xv.z - mu) * rstd * lg.z + lb.z) * (gv.z * sigmoidf_(gv.z)));
  u.w = f2bf(((xv.w - mu) * rstd * lg.w + lb.w) * (gv.w * sigmoidf_(gv.w)));
  *(ushort4*)(y + row + tid * 4) = u;
}

extern "C" void kernel_launch(void* const* d_in, const int* in_sizes, int n_in,
                              void* d_out, int out_size, void* d_ws, size_t ws_size,
                              hipStream_t stream) {
  const float* x    = (const float*)d_in[0];
  const float* Wq   = (const float*)d_in[1];
  const float* Wk   = (const float*)d_in[2];
  const float* Wv   = (const float*)d_in[3];
  const float* Wa   = (const float*)d_in[4];
  const float* ba   = (const float*)d_in[5];
  const float* Wb   = (const float*)d_in[6];
  const float* bb   = (const float*)d_in[7];
  const float* Wg   = (const float*)d_in[8];
  const float* Wo   = (const float*)d_in[9];
  const float* ln_g = (const float*)d_in[10];
  const float* ln_b = (const float*)d_in[11];
  float* out = (float*)d_out;
  char* ws = (char*)d_ws;

  u16*   wb  = (u16*)(ws + OFF_WB);
  u16*   xb  = (u16*)(ws + OFF_XB);   // x-bf16 -> Qc -> y-bf16
  float* qf  = (float*)(ws + OFF_Q);
  float* kf  = (float*)(ws + OFF_K);
  float* vf  = (float*)(ws + OFF_V);
  float* gf  = (float*)(ws + OFF_G);
  float* al  = (float*)(ws + OFF_AL);
  float* be  = (float*)(ws + OFF_BE);
  u16*   wab = (u16*)(ws + OFF_P);    // Wab bf16 (32x1024) during GEMM; region later becomes P
  float* Pb  = (float*)(ws + OFF_P);
  float* Qc  = (float*)(ws + OFF_XB); // reuses dead x-bf16 region
  float* of  = (float*)(ws + OFF_O);
  u16*   yb  = xb;

  cvt_x_kernel<<<8192, 256, 0, stream>>>(x, xb);
  cvt_w_kernel<<<dim3(1024, 1, 5), 256, 0, stream>>>(Wq, Wk, Wv, Wg, Wo, wb);
  cvt_ab_kernel<<<32, 256, 0, stream>>>(Wa, Wb, wab);
  // alpha/beta: tiny dedicated MFMA GEMM (64 blocks, ~5 us)
  ab_gemm<<<64, 256, 0, stream>>>(xb, wab, al, be, ba, bb);
  // projections q,k,v,g: 256x256 8-phase MFMA GEMM, fused epilogues; 512 blocks = 2 clean generations
  gemm256<<<512, 512, 0, stream>>>(xb, wb, qf, kf, vf, gf, 1);
  // chunked scan: 1 chunk/block, 4 row-split waves, 1024 blocks -> 4 blocks/CU
  scan_p1<<<1024, 256, 0, stream>>>(kf, vf, al, be, Pb, Qc);
  scan_comb<<<1024, 256, 0, stream>>>(Pb, Qc);
  scan_p2<<<1024, 256, 0, stream>>>(qf, kf, vf, al, be, Pb, of);
  // epilogue
  ln_gate_kernel<<<8192, 256, 0, stream>>>(of, gf, ln_g, ln_b, yb);
  gemm256<<<128, 512, 0, stream>>>(yb, wb + (size_t)4 * 1024 * 1024, out, out, out, out, 0);
}

// Round 4
// 1430.507 us; speedup vs baseline: 1.0515x; 1.0515x over previous
//
#include <hip/hip_runtime.h>

typedef unsigned short u16;
typedef __bf16 bf16x8 __attribute__((ext_vector_type(8)));
typedef float f32x4 __attribute__((ext_vector_type(4)));

constexpr int Bq  = 4;
constexpr int Sq  = 2048;
constexpr int Hq  = 1024;
constexpr int NHq = 16;
constexpr int HDq = 64;
constexpr int CCH = 16;    // chunks
constexpr int LCH = 128;   // chunk length

// workspace layout (bytes), total 212,860,928
constexpr size_t OFF_WB = 0;             // W bf16: 5*1M*2 = 10,485,760
constexpr size_t OFF_XB = 10485760;      // 16,777,216: x-bf16 -> Qc (scan) -> y-bf16 (epilogue)
constexpr size_t OFF_Q  = 27262976;      // q fp32: 33,554,432
constexpr size_t OFF_K  = 60817408;
constexpr size_t OFF_V  = 94371840;
constexpr size_t OFF_G  = 127926272;
constexpr size_t OFF_AL = 161480704;     // alpha: 524,288
constexpr size_t OFF_BE = 162004992;
constexpr size_t OFF_P  = 162529280;     // Wab bf16 (64 KB, 32 rows) during GEMM -> chunk P (16 MB) during scan
constexpr size_t OFF_O  = 179306496;     // of fp32: 33,554,432 (end 212,860,928)

__device__ __forceinline__ u16 f2bf(float f) {
  unsigned u = __float_as_uint(f);
  u += 0x7fffu + ((u >> 16) & 1u);
  return (u16)(u >> 16);
}
__device__ __forceinline__ float sigmoidf_(float x) { return 1.f / (1.f + __expf(-x)); }

__device__ __forceinline__ void async16(const void* g, void* l) {
  __builtin_amdgcn_global_load_lds((const __attribute__((address_space(1))) void*)g,
                                   (__attribute__((address_space(3))) void*)l, 16, 0, 0);
}

// ---------------- converts ----------------
__global__ __launch_bounds__(256) void cvt_x_kernel(const float* __restrict__ in, u16* __restrict__ outp) {
  const size_t i = ((size_t)blockIdx.x * 256 + threadIdx.x) * 4;
  float4 f = *(const float4*)(in + i);
  ushort4 u; u.x = f2bf(f.x); u.y = f2bf(f.y); u.z = f2bf(f.z); u.w = f2bf(f.w);
  *(ushort4*)(outp + i) = u;
}

__global__ __launch_bounds__(256) void cvt_w_kernel(const float* __restrict__ w0, const float* __restrict__ w1,
    const float* __restrict__ w2, const float* __restrict__ w3, const float* __restrict__ w4,
    u16* __restrict__ outp) {
  const int z = blockIdx.z;
  const float* src = (z == 0) ? w0 : (z == 1) ? w1 : (z == 2) ? w2 : (z == 3) ? w3 : w4;
  const size_t i = ((size_t)blockIdx.x * 256 + threadIdx.x) * 4;
  float4 f = *(const float4*)(src + i);
  ushort4 u; u.x = f2bf(f.x); u.y = f2bf(f.y); u.z = f2bf(f.z); u.w = f2bf(f.w);
  *(ushort4*)(outp + (size_t)z * (1024 * 1024) + i) = u;
}

// Wab: 32x1024 bf16; rows 0..15 = Wa, 16..31 = Wb
__global__ __launch_bounds__(256) void cvt_ab_kernel(const float* __restrict__ Wa, const float* __restrict__ Wb,
    u16* __restrict__ outp) {
  const size_t i = ((size_t)blockIdx.x * 256 + threadIdx.x) * 4;
  const int row = (int)(i >> 10);
  const float* src = (row < 16) ? (Wa + i) : (Wb + i - 16 * 1024);
  float4 f = *(const float4*)src;
  ushort4 u; u.x = f2bf(f.x); u.y = f2bf(f.y); u.z = f2bf(f.z); u.w = f2bf(f.w);
  *(ushort4*)(outp + i) = u;
}

// ---------------- alpha/beta GEMM: 8192x32 = x @ [Wa;Wb]^T, tiny, MFMA direct-from-global ----------------
__global__ __launch_bounds__(256) void ab_gemm(const u16* __restrict__ A, const u16* __restrict__ Wab,
    float* __restrict__ al, float* __restrict__ be, const float* __restrict__ ba, const float* __restrict__ bb) {
  const int tid = threadIdx.x, wv = tid >> 6, lane = tid & 63;
  const int l15 = lane & 15, qd = lane >> 4;
  const int m0 = blockIdx.x * 128 + wv * 32;
  const u16* gA = A + (size_t)m0 * 1024 + qd * 8;
  const u16* gB = Wab + (size_t)l15 * 1024 + qd * 8;
  f32x4 acc[2][2] = {};
#pragma unroll 4
  for (int kt = 0; kt < 1024; kt += 32) {
    bf16x8 a0 = *(const bf16x8*)(gA + (size_t)l15 * 1024 + kt);
    bf16x8 a1 = *(const bf16x8*)(gA + (size_t)(16 + l15) * 1024 + kt);
    bf16x8 b0 = *(const bf16x8*)(gB + kt);
    bf16x8 b1 = *(const bf16x8*)(gB + 16 * 1024 + kt);
    acc[0][0] = __builtin_amdgcn_mfma_f32_16x16x32_bf16(a0, b0, acc[0][0], 0, 0, 0);
    acc[0][1] = __builtin_amdgcn_mfma_f32_16x16x32_bf16(a0, b1, acc[0][1], 0, 0, 0);
    acc[1][0] = __builtin_amdgcn_mfma_f32_16x16x32_bf16(a1, b0, acc[1][0], 0, 0, 0);
    acc[1][1] = __builtin_amdgcn_mfma_f32_16x16x32_bf16(a1, b1, acc[1][1], 0, 0, 0);
  }
  const float bav = ba[l15], bbv = bb[l15];
#pragma unroll
  for (int mi = 0; mi < 2; ++mi) {
    const int row = m0 + mi * 16 + qd * 4;
#pragma unroll
    for (int r = 0; r < 4; ++r) {
      al[(size_t)(row + r) * 16 + l15] = sigmoidf_(acc[mi][0][r] + bav);
      be[(size_t)(row + r) * 16 + l15] = sigmoidf_(acc[mi][1][r] + bbv);
    }
  }
}

// ============ 256x256 8-phase bf16 MFMA GEMM (T1+T2+T3+T4+T5) with fused epilogues ============
__device__ __forceinline__ void lda4(bf16x8 af[4][2], const u16* LA, int wr, int mh, int l15, int qd, int l7) {
#pragma unroll
  for (int i = 0; i < 4; ++i)
#pragma unroll
    for (int kk = 0; kk < 2; ++kk)
      af[i][kk] = *(const bf16x8*)(LA + (wr * 128 + mh * 64 + i * 16 + l15) * 64 + (((kk * 4 + qd) ^ l7) * 8));
}
__device__ __forceinline__ void ldb2(bf16x8 bf[2][2], const u16* LB, int wc, int nh, int l15, int qd, int l7) {
#pragma unroll
  for (int j = 0; j < 2; ++j)
#pragma unroll
    for (int kk = 0; kk < 2; ++kk)
      bf[j][kk] = *(const bf16x8*)(LB + (wc * 64 + nh * 32 + j * 16 + l15) * 64 + (((kk * 4 + qd) ^ l7) * 8));
}
__device__ __forceinline__ void mm16(f32x4 acc[8][4], const bf16x8 af[4][2], const bf16x8 bf[2][2], int mh, int nh) {
#pragma unroll
  for (int i = 0; i < 4; ++i)
#pragma unroll
    for (int j = 0; j < 2; ++j) {
      f32x4 c = acc[mh * 4 + i][nh * 2 + j];
      c = __builtin_amdgcn_mfma_f32_16x16x32_bf16(af[i][0], bf[j][0], c, 0, 0, 0);
      c = __builtin_amdgcn_mfma_f32_16x16x32_bf16(af[i][1], bf[j][1], c, 0, 0, 0);
      acc[mh * 4 + i][nh * 2 + j] = c;
    }
}
__device__ __forceinline__ void stageH(u16* LD, int bufp, int mat, int h, const u16* gRow0, int kElem,
                                       int rr, int sl8, int wv) {
  const u16* s0 = gRow0 + (size_t)(h * 128 + rr) * 1024 + kElem + sl8;
  u16* d = LD + bufp * 32768 + mat * 16384 + h * 8192 + wv * 512;
  async16(s0, d);
  async16(s0 + (size_t)(64 * 1024), d + 4096);
}

template<int S1, int S2, int VM>
__device__ __forceinline__ void tile16(u16* LD, int bp, int kt,
    const u16* gA, const u16* gB, f32x4 acc[8][4], bf16x8 af[4][2], bf16x8 bf0[2][2], bf16x8 bf1[2][2],
    int wr, int wc, int l15, int qd, int l7, int rr, int sl8, int wv) {
  const u16* LA = LD + bp * 32768;
  const u16* LB = LA + 16384;
  // ---- ph0: quadrant (mh0, nh0); stage A-h0(t+1)
  lda4(af, LA, wr, 0, l15, qd, l7);
  ldb2(bf0, LB, wc, 0, l15, qd, l7);
  if (S1) stageH(LD, bp ^ 1, 0, 0, gA, (kt + 1) * 64, rr, sl8, wv);
  __builtin_amdgcn_s_barrier();
  asm volatile("s_waitcnt lgkmcnt(0)" ::: "memory");
  __builtin_amdgcn_sched_barrier(0);
  __builtin_amdgcn_s_setprio(1);
  mm16(acc, af, bf0, 0, 0);
  __builtin_amdgcn_s_setprio(0);
  __builtin_amdgcn_s_barrier();
  // ---- ph1: (mh0, nh1); stage A-h1(t+1)
  ldb2(bf1, LB, wc, 1, l15, qd, l7);
  if (S1) stageH(LD, bp ^ 1, 0, 1, gA, (kt + 1) * 64, rr, sl8, wv);
  __builtin_amdgcn_s_barrier();
  asm volatile("s_waitcnt lgkmcnt(0)" ::: "memory");
  __builtin_amdgcn_sched_barrier(0);
  __builtin_amdgcn_s_setprio(1);
  mm16(acc, af, bf1, 0, 1);
  __builtin_amdgcn_s_setprio(0);
  __builtin_amdgcn_s_barrier();
  // ---- ph2: (mh1, nh0); stage B-h0(t+2)
  lda4(af, LA, wr, 1, l15, qd, l7);
  if (S2) stageH(LD, bp, 1, 0, gB, (kt + 2) * 64, rr, sl8, wv);
  __builtin_amdgcn_s_barrier();
  asm volatile("s_waitcnt lgkmcnt(0)" ::: "memory");
  __builtin_amdgcn_sched_barrier(0);
  __builtin_amdgcn_s_setprio(1);
  mm16(acc, af, bf0, 1, 0);
  __builtin_amdgcn_s_setprio(0);
  __builtin_amdgcn_s_barrier();
  // ---- ph3: (mh1, nh1); stage B-h1(t+2); boundary counted-vmcnt then barrier
  if (S2) stageH(LD, bp, 1, 1, gB, (kt + 2) * 64, rr, sl8, wv);
  __builtin_amdgcn_s_barrier();
  __builtin_amdgcn_sched_barrier(0);
  __builtin_amdgcn_s_setprio(1);
  mm16(acc, af, bf1, 1, 1);
  __builtin_amdgcn_s_setprio(0);
  if (VM == 4) asm volatile("s_waitcnt vmcnt(4)" ::: "memory");
  else if (VM == 0) asm volatile("s_waitcnt vmcnt(0)" ::: "memory");
  __builtin_amdgcn_s_barrier();
}

// mode 0: plain store to Cq (final out-proj), grid 128.
// mode 1: z = q,k,v,g with fused l2norm/l2norm/silu/plain epilogues, grid 512.
__global__ __launch_bounds__(512, 2) void gemm256(const u16* __restrict__ A, const u16* __restrict__ Wall,
    float* __restrict__ Cq, float* __restrict__ Ck, float* __restrict__ Cv, float* __restrict__ Cg,
    int mode) {
  __shared__ __align__(16) u16 Lds[65536];   // 128 KiB: [buf][A|B][256][64] bf16
  u16* LD = &Lds[0];
  const int tid = threadIdx.x;
  const int wv = tid >> 6, lane = tid & 63;
  const int l15 = lane & 15, qd = lane >> 4, l7 = l15 & 7;
  const int wr = wv >> 2, wc = wv & 3;
  const int rr = tid >> 3, sl8 = ((tid & 7) ^ (rr & 7)) * 8;

  // T1 bijective XCD swizzle (grid % 8 == 0): jobs ordered (z,ny major, mx minor).
  int mx, ny, z;
  const u16* Wm;
  if (mode == 0) {
    const int job = ((blockIdx.x & 7) << 4) + (blockIdx.x >> 3);   // 128 jobs
    mx = job & 31; ny = job >> 5; z = 0; Wm = Wall;
  } else {
    const int job = ((blockIdx.x & 7) << 6) + (blockIdx.x >> 3);   // 512 jobs
    mx = job & 31; ny = (job >> 5) & 3; z = job >> 7;
    Wm = Wall + (size_t)z * (1024 * 1024);
  }
  const int m0 = mx * 256, n0 = ny * 256;
  const u16* gA = A + (size_t)m0 * 1024;
  const u16* gB = Wm + (size_t)n0 * 1024;

  f32x4 acc[8][4] = {};
  bf16x8 af[4][2], bf0[2][2], bf1[2][2];

  // prologue: tile0 all 4 halves -> buf0; tile1 B halves -> buf1; wait tile0 landed (4 loads in flight)
  stageH(LD, 0, 0, 0, gA, 0,  rr, sl8, wv);
  stageH(LD, 0, 0, 1, gA, 0,  rr, sl8, wv);
  stageH(LD, 0, 1, 0, gB, 0,  rr, sl8, wv);
  stageH(LD, 0, 1, 1, gB, 0,  rr, sl8, wv);
  stageH(LD, 1, 1, 0, gB, 64, rr, sl8, wv);
  stageH(LD, 1, 1, 1, gB, 64, rr, sl8, wv);
  asm volatile("s_waitcnt vmcnt(4)" ::: "memory");
  __builtin_amdgcn_s_barrier();

  // 16 K-tiles (K=1024, BK=64); 2 tiles per iter so buffer parity is compile-time
#pragma unroll 1
  for (int t2 = 0; t2 < 7; ++t2) {
    tile16<1, 1, 4>(LD, 0, 2 * t2,     gA, gB, acc, af, bf0, bf1, wr, wc, l15, qd, l7, rr, sl8, wv);
    tile16<1, 1, 4>(LD, 1, 2 * t2 + 1, gA, gB, acc, af, bf0, bf1, wr, wc, l15, qd, l7, rr, sl8, wv);
  }
  tile16<1, 0, 0>(LD, 0, 14, gA, gB, acc, af, bf0, bf1, wr, wc, l15, qd, l7, rr, sl8, wv);
  tile16<0, 0, -1>(LD, 1, 15, gA, gB, acc, af, bf0, bf1, wr, wc, l15, qd, l7, rr, sl8, wv);

  // ---- epilogues ---- C/D layout per 16x16 frag: col = l15, row = qd*4 + r
  if (mode == 1 && z <= 1) {
#pragma unroll
    for (int mi = 0; mi < 8; ++mi)
#pragma unroll
      for (int r = 0; r < 4; ++r) {
        float ss = acc[mi][0][r] * acc[mi][0][r] + acc[mi][1][r] * acc[mi][1][r]
                 + acc[mi][2][r] * acc[mi][2][r] + acc[mi][3][r] * acc[mi][3][r];
        ss += __shfl_xor(ss, 1); ss += __shfl_xor(ss, 2);
        ss += __shfl_xor(ss, 4); ss += __shfl_xor(ss, 8);
        const float rn = 1.f / fmaxf(sqrtf(ss), 1e-12f);
        acc[mi][0][r] *= rn; acc[mi][1][r] *= rn; acc[mi][2][r] *= rn; acc[mi][3][r] *= rn;
      }
  } else if (mode == 1 && z == 2) {
#pragma unroll
    for (int mi = 0; mi < 8; ++mi)
#pragma unroll
      for (int ni = 0; ni < 4; ++ni)
#pragma unroll
        for (int r = 0; r < 4; ++r)
          acc[mi][ni][r] = acc[mi][ni][r] * sigmoidf_(acc[mi][ni][r]);
  }
  float* C = (mode == 0) ? Cq : ((z == 0) ? Cq : (z == 1) ? Ck : (z == 2) ? Cv : Cg);
#pragma unroll
  for (int mi = 0; mi < 8; ++mi) {
    const int row = m0 + wr * 128 + mi * 16 + qd * 4;
#pragma unroll
    for (int ni = 0; ni < 4; ++ni) {
      const int col = n0 + wc * 64 + ni * 16 + l15;
#pragma unroll
      for (int r = 0; r < 4; ++r)
        C[(size_t)(row + r) * 1024 + col] = acc[mi][ni][r];
    }
  }
}

// ================= chunked scan: 1 chunk/block, 4 row-split waves (4 blocks/CU) =================
// Software-pipelined across tokens, with sched_barrier(0) PINNING each token iteration:
// without the pin, LLVM hoists all 15 prefetch LDS loads to the tile top (they have no
// dependence on the compute) -> live-range explosion -> scratch spill (r3: 4.1 GB traffic).
struct ScanLds1 { float kb[2][16 * 64]; float vb[2][16 * 64]; float ab[2][32]; };
struct ScanLds2 { float kb[2][16 * 64]; float qb[2][16 * 64]; float vb[2][16 * 64]; float ab[2][32]; };

// pass 1: compose affine maps over the chunk (Pr/Qr, 2x8 tile per lane)
__global__ __launch_bounds__(256, 4) void scan_p1(const float* __restrict__ k, const float* __restrict__ v,
    const float* __restrict__ al, const float* __restrict__ be,
    float* __restrict__ P, float* __restrict__ Q) {
  __shared__ ScanLds1 L;
  const int tid = threadIdx.x, wv = tid >> 6, lane = tid & 63;
  const int bh = blockIdx.x >> 4, c = blockIdx.x & 15;
  const int b = bh >> 4, h = bh & 15;
  const int rg = lane >> 3, cg = lane & 7;
  const int r0 = wv * 16 + rg * 2, c8 = cg * 8;
  const size_t base0 = ((size_t)(b * Sq + c * LCH)) * 1024 + h * 64;
  const size_t ab0   = ((size_t)(b * Sq + c * LCH)) * 16 + h;
  const int tokw = lane >> 4, seg = lane & 15;
  auto stage = [&](int tile, int bi) {
    #pragma unroll
    for (int j = 0; j < 2; ++j) {        // 8 jobs: (arr{k,v}, quarter)
      const int job = wv * 2 + j;
      const int arr = job >> 2, i = job & 3;
      const float* src = arr ? v : k;
      float* dst = arr ? &L.vb[bi][i * 256] : &L.kb[bi][i * 256];
      async16(src + base0 + (size_t)(tile * 16 + i * 4 + tokw) * 1024 + seg * 4, dst);
    }
    if (wv == 0 && lane < 32) {          // a/b: 32 values, one lane each
      const int w16 = lane >> 4, tt = lane & 15;
      const float* s = w16 ? be : al;
      L.ab[bi][w16 * 16 + tt] = s[ab0 + (size_t)(tile * 16 + tt) * 16];
    }
  };
  float Pr[16], Qr[16];
  #pragma unroll
  for (int i = 0; i < 16; ++i) { Pr[i] = 1.f; Qr[i] = 0.f; }
  stage(0, 0);
  for (int tile = 0; tile < 8; ++tile) {
    __syncthreads();
    if (tile < 7) stage(tile + 1, (tile + 1) & 1);
    const int bi = tile & 1;
    const float* kbp = L.kb[bi];
    const float* vbp = L.vb[bi];
    const float* abp = L.ab[bi];
    float4 kc0 = *(const float4*)(kbp + c8);
    float4 kc1 = *(const float4*)(kbp + c8 + 4);
    float2 krp = *(const float2*)(kbp + r0);
    float2 vrp = *(const float2*)(vbp + r0);
    float  ap = abp[0], btp = abp[16];
    #pragma unroll
    for (int tt = 0; tt < 16; ++tt) {
      float4 nk0, nk1; float2 nkr, nvr; float na, nbt;
      if (tt < 15) {   // prefetch token tt+1 under token tt's compute
        const float* kq = kbp + (tt + 1) * 64;
        nk0 = *(const float4*)(kq + c8);
        nk1 = *(const float4*)(kq + c8 + 4);
        nkr = *(const float2*)(kq + r0);
        nvr = *(const float2*)(vbp + (tt + 1) * 64 + r0);
        na  = abp[tt + 1]; nbt = abp[16 + tt + 1];
      }
      const float kcv[8] = {kc0.x, kc0.y, kc0.z, kc0.w, kc1.x, kc1.y, kc1.z, kc1.w};
      const float abt = ap * btp;
      const float c1a = abt * krp.x, c1b = abt * krp.y;
      const float c2a = btp * vrp.x, c2b = btp * vrp.y;
      #pragma unroll
      for (int j = 0; j < 8; ++j) {
        const float A0 = fmaf(-c1a, kcv[j], ap);
        Qr[j] = fmaf(A0, Qr[j], c2a * kcv[j]);
        Pr[j] *= A0;
        const float A1 = fmaf(-c1b, kcv[j], ap);
        Qr[8 + j] = fmaf(A1, Qr[8 + j], c2b * kcv[j]);
        Pr[8 + j] *= A1;
      }
      if (tt < 15) { kc0 = nk0; kc1 = nk1; krp = nkr; vrp = nvr; ap = na; btp = nbt; }
      __builtin_amdgcn_sched_barrier(0);   // pin: next iteration's prefetch cannot hoist above
    }
  }
  const size_t pbase = ((size_t)bh * CCH + c) * 4096 + (size_t)c8;
  #pragma unroll
  for (int i = 0; i < 2; ++i) {
    const size_t pi = pbase + (size_t)(r0 + i) * 64;
    *(float4*)(P + pi)     = make_float4(Pr[i*8],   Pr[i*8+1], Pr[i*8+2], Pr[i*8+3]);
    *(float4*)(P + pi + 4) = make_float4(Pr[i*8+4], Pr[i*8+5], Pr[i*8+6], Pr[i*8+7]);
    *(float4*)(Q + pi)     = make_float4(Qr[i*8],   Qr[i*8+1], Qr[i*8+2], Qr[i*8+3]);
    *(float4*)(Q + pi + 4) = make_float4(Qr[i*8+4], Qr[i*8+5], Qr[i*8+6], Qr[i*8+7]);
  }
}

// pass 2: sequential combine over chunks; writes chunk-initial state over P
__global__ __launch_bounds__(256) void scan_comb(float* __restrict__ P, const float* __restrict__ Q) {
  const int g = blockIdx.x * 256 + threadIdx.x;  // 0..262143
  const int elem = g & 4095;
  const int bh = g >> 12;
  float s = 0.f;
  #pragma unroll
  for (int c = 0; c < CCH; ++c) {
    const size_t idx = ((size_t)bh * CCH + c) * 4096 + elem;
    const float p = P[idx], qq = Q[idx];
    P[idx] = s;
    s = fmaf(p, s, qq);
  }
}

// pass 3: re-iterate chunk from s_init, emit outputs
__global__ __launch_bounds__(256, 4) void scan_p2(const float* __restrict__ q, const float* __restrict__ k,
    const float* __restrict__ v, const float* __restrict__ al, const float* __restrict__ be,
    const float* __restrict__ Pini, float* __restrict__ o) {
  __shared__ ScanLds2 L;
  const int tid = threadIdx.x, wv = tid >> 6, lane = tid & 63;
  const int bh = blockIdx.x >> 4, c = blockIdx.x & 15;
  const int b = bh >> 4, h = bh & 15;
  const int rg = lane >> 3, cg = lane & 7;
  const int r0 = wv * 16 + rg * 2, c8 = cg * 8;
  const size_t base0 = ((size_t)(b * Sq + c * LCH)) * 1024 + h * 64;
  const size_t ab0   = ((size_t)(b * Sq + c * LCH)) * 16 + h;
  const size_t pbase = ((size_t)bh * CCH + c) * 4096 + (size_t)c8;
  const int tokw = lane >> 4, seg = lane & 15;
  auto stage = [&](int tile, int bi) {
    #pragma unroll
    for (int j = 0; j < 3; ++j) {        // 12 jobs: (arr{k,q,v}, quarter)
      const int job = wv * 3 + j;
      const int arr = job >> 2, i = job & 3;
      const float* src = (arr == 0) ? k : (arr == 1) ? q : v;
      float* dst = (arr == 0) ? &L.kb[bi][i * 256] : (arr == 1) ? &L.qb[bi][i * 256]
                                                                : &L.vb[bi][i * 256];
      async16(src + base0 + (size_t)(tile * 16 + i * 4 + tokw) * 1024 + seg * 4, dst);
    }
    if (wv == 0 && lane < 32) {
      const int w16 = lane >> 4, tt = lane & 15;
      const float* s = w16 ? be : al;
      L.ab[bi][w16 * 16 + tt] = s[ab0 + (size_t)(tile * 16 + tt) * 16];
    }
  };
  float st[16];
  #pragma unroll
  for (int i = 0; i < 2; ++i) {
    float4 s0 = *(const float4*)(Pini + pbase + (size_t)(r0 + i) * 64);
    float4 s1 = *(const float4*)(Pini + pbase + (size_t)(r0 + i) * 64 + 4);
    st[i*8]   = s0.x; st[i*8+1] = s0.y; st[i*8+2] = s0.z; st[i*8+3] = s0.w;
    st[i*8+4] = s1.x; st[i*8+5] = s1.y; st[i*8+6] = s1.z; st[i*8+7] = s1.w;
  }
  stage(0, 0);
  const bool hi4 = (cg & 4);
  const int rowIdx = r0 + (cg >> 2);
  const bool doStore = ((cg & 3) == 0);
  for (int tile = 0; tile < 8; ++tile) {
    __syncthreads();
    if (tile < 7) stage(tile + 1, (tile + 1) & 1);
    const int bi = tile & 1;
    const float* kbp = L.kb[bi];
    const float* qbp = L.qb[bi];
    const float* vbp = L.vb[bi];
    const float* abp = L.ab[bi];
    float4 kc0 = *(const float4*)(kbp + c8);
    float4 kc1 = *(const float4*)(kbp + c8 + 4);
    float4 qc0 = *(const float4*)(qbp + c8);
    float4 qc1 = *(const float4*)(qbp + c8 + 4);
    float2 krp = *(const float2*)(kbp + r0);
    float2 vrp = *(const float2*)(vbp + r0);
    float  ap = abp[0], btp = abp[16];
    #pragma unroll
    for (int tt = 0; tt < 16; ++tt) {
      float4 nk0, nk1, nq0, nq1; float2 nkr, nvr; float na, nbt;
      if (tt < 15) {   // prefetch token tt+1 under token tt's compute
        const float* kq = kbp + (tt + 1) * 64;
        const float* qq = qbp + (tt + 1) * 64;
        nk0 = *(const float4*)(kq + c8);
        nk1 = *(const float4*)(kq + c8 + 4);
        nq0 = *(const float4*)(qq + c8);
        nq1 = *(const float4*)(qq + c8 + 4);
        nkr = *(const float2*)(kq + r0);
        nvr = *(const float2*)(vbp + (tt + 1) * 64 + r0);
        na  = abp[tt + 1]; nbt = abp[16 + tt + 1];
      }
      const int t = tile * 16 + tt;
      const float kcv[8] = {kc0.x, kc0.y, kc0.z, kc0.w, kc1.x, kc1.y, kc1.z, kc1.w};
      const float qcv[8] = {qc0.x, qc0.y, qc0.z, qc0.w, qc1.x, qc1.y, qc1.z, qc1.w};
      const float abt = ap * btp;
      const float c1a = abt * krp.x, c1b = abt * krp.y;
      const float c2a = btp * vrp.x, c2b = btp * vrp.y;
      float p0 = 0.f, p1v = 0.f;
      #pragma unroll
      for (int j = 0; j < 8; ++j) {
        const float A0 = fmaf(-c1a, kcv[j], ap);
        st[j] = fmaf(A0, st[j], c2a * kcv[j]);
        p0 = fmaf(st[j], qcv[j], p0);
        const float A1 = fmaf(-c1b, kcv[j], ap);
        st[8 + j] = fmaf(A1, st[8 + j], c2b * kcv[j]);
        p1v = fmaf(st[8 + j], qcv[j], p1v);
      }
      // reduce over the 8 col-lanes: keep-one/send-one split at xor4, then xor2/xor1.
      float my    = hi4 ? p1v : p0;
      float other = hi4 ? p0 : p1v;
      my += __shfl_xor(other, 4);
      my += __shfl_xor(my, 2);
      my += __shfl_xor(my, 1);
      if (doStore) o[base0 + (size_t)t * 1024 + rowIdx] = my;
      if (tt < 15) { kc0 = nk0; kc1 = nk1; qc0 = nq0; qc1 = nq1; krp = nkr; vrp = nvr; ap = na; btp = nbt; }
      __builtin_amdgcn_sched_barrier(0);   // pin: next iteration's prefetch cannot hoist above
    }
  }
}

// ---------------- LayerNorm + silu-gate, write bf16 ----------------
__global__ __launch_bounds__(256) void ln_gate_kernel(const float* __restrict__ o, const float* __restrict__ g,
    const float* __restrict__ ln_g, const float* __restrict__ ln_b, u16* __restrict__ y) {
  const int t = blockIdx.x, tid = threadIdx.x;
  const size_t row = (size_t)t * 1024;
  float4 xv = *(const float4*)(o + row + tid * 4);
  float s  = xv.x + xv.y + xv.z + xv.w;
  float s2 = xv.x * xv.x + xv.y * xv.y + xv.z * xv.z + xv.w * xv.w;
  #pragma unroll
  for (int m = 1; m < 64; m <<= 1) { s += __shfl_xor(s, m); s2 += __shfl_xor(s2, m); }
  __shared__ float red[8];
  const int w = tid >> 6, lane = tid & 63;
  if (lane == 0) { red[w] = s; red[4 + w] = s2; }
  __syncthreads();
  s  = red[0] + red[1] + red[2] + red[3];
  s2 = red[4] + red[5] + red[6] + red[7];
  const float mu = s * (1.f / 1024.f);
  const float var = s2 * (1.f / 1024.f) - mu * mu;
  const float rstd = rsqrtf(var + 1e-5f);
  float4 gv = *(const float4*)(g + row + tid * 4);
  float4 lg = *(const float4*)(ln_g + tid * 4);
  float4 lb = *(const float4*)(ln_b + tid * 4);
  ushort4 u;
  u.x = f2bf(((xv.x - mu) * rstd * lg.x + lb.x) * (gv.x * sigmoidf_(gv.x)));
  u.y = f2bf(((xv.y - mu) * rstd * lg.y + lb.y) * (gv.y * sigmoidf_(gv.y)));
  u.z = f2bf(((xv.z - mu) * rstd * lg.z + lb.z) * (gv.z * sigmoidf_(gv.z)));
  u.w = f2bf(((xv.w - mu) * rstd * lg.w + lb.w) * (gv.w * sigmoidf_(gv.w)));
  *(ushort4*)(y + row + tid * 4) = u;
}

extern "C" void kernel_launch(void* const* d_in, const int* in_sizes, int n_in,
                              void* d_out, int out_size, void* d_ws, size_t ws_size,
                              hipStream_t stream) {
  const float* x    = (const float*)d_in[0];
  const float* Wq   = (const float*)d_in[1];
  const float* Wk   = (const float*)d_in[2];
  const float* Wv   = (const float*)d_in[3];
  const float* Wa   = (const float*)d_in[4];
  const float* ba   = (const float*)d_in[5];
  const float* Wb   = (const float*)d_in[6];
  const float* bb   = (const float*)d_in[7];
  const float* Wg   = (const float*)d_in[8];
  const float* Wo   = (const float*)d_in[9];
  const float* ln_g = (const float*)d_in[10];
  const float* ln_b = (const float*)d_in[11];
  float* out = (float*)d_out;
  char* ws = (char*)d_ws;

  u16*   wb  = (u16*)(ws + OFF_WB);
  u16*   xb  = (u16*)(ws + OFF_XB);   // x-bf16 -> Qc -> y-bf16
  float* qf  = (float*)(ws + OFF_Q);
  float* kf  = (float*)(ws + OFF_K);
  float* vf  = (float*)(ws + OFF_V);
  float* gf  = (float*)(ws + OFF_G);
  float* al  = (float*)(ws + OFF_AL);
  float* be  = (float*)(ws + OFF_BE);
  u16*   wab = (u16*)(ws + OFF_P);    // Wab bf16 (32x1024) during GEMM; region later becomes P
  float* Pb  = (float*)(ws + OFF_P);
  float* Qc  = (float*)(ws + OFF_XB); // reuses dead x-bf16 region
  float* of  = (float*)(ws + OFF_O);
  u16*   yb  = xb;

  cvt_x_kernel<<<8192, 256, 0, stream>>>(x, xb);
  cvt_w_kernel<<<dim3(1024, 1, 5), 256, 0, stream>>>(Wq, Wk, Wv, Wg, Wo, wb);
  cvt_ab_kernel<<<32, 256, 0, stream>>>(Wa, Wb, wab);
  // alpha/beta: tiny dedicated MFMA GEMM (64 blocks, ~5 us)
  ab_gemm<<<64, 256, 0, stream>>>(xb, wab, al, be, ba, bb);
  // projections q,k,v,g: 256x256 8-phase MFMA GEMM, fused epilogues; 512 blocks = 2 clean generations
  gemm256<<<512, 512, 0, stream>>>(xb, wb, qf, kf, vf, gf, 1);
  // chunked scan: 1 chunk/block, 4 row-split waves, 1024 blocks -> 4 blocks/CU
  scan_p1<<<1024, 256, 0, stream>>>(kf, vf, al, be, Pb, Qc);
  scan_comb<<<1024, 256, 0, stream>>>(Pb, Qc);
  scan_p2<<<1024, 256, 0, stream>>>(qf, kf, vf, al, be, Pb, of);
  // epilogue
  ln_gate_kernel<<<8192, 256, 0, stream>>>(of, gf, ln_g, ln_b, yb);
  gemm256<<<128, 512, 0, stream>>>(yb, wb + (size_t)4 * 1024 * 1024, out, out, out, out, 0);
}

// Round 5
// 419.232 us; speedup vs baseline: 3.5880x; 3.4122x over previous
//
#include <hip/hip_runtime.h>

typedef unsigned short u16;
typedef __bf16 bf16x8 __attribute__((ext_vector_type(8)));
typedef float f32x4 __attribute__((ext_vector_type(4)));

constexpr int Bq  = 4;
constexpr int Sq  = 2048;
constexpr int Hq  = 1024;
constexpr int NHq = 16;
constexpr int HDq = 64;
constexpr int CCH = 16;    // chunks
constexpr int LCH = 128;   // chunk length

// workspace layout (bytes), total 212,860,928
constexpr size_t OFF_WB = 0;             // W bf16: 5*1M*2 = 10,485,760
constexpr size_t OFF_XB = 10485760;      // 16,777,216: x-bf16 -> Qc (scan) -> y-bf16 (epilogue)
constexpr size_t OFF_Q  = 27262976;      // q fp32: 33,554,432
constexpr size_t OFF_K  = 60817408;
constexpr size_t OFF_V  = 94371840;
constexpr size_t OFF_G  = 127926272;
constexpr size_t OFF_AL = 161480704;     // alpha: 524,288
constexpr size_t OFF_BE = 162004992;
constexpr size_t OFF_P  = 162529280;     // Wab bf16 (64 KB, 32 rows) during GEMM -> chunk P (16 MB) during scan
constexpr size_t OFF_O  = 179306496;     // of fp32: 33,554,432 (end 212,860,928)

__device__ __forceinline__ u16 f2bf(float f) {
  unsigned u = __float_as_uint(f);
  u += 0x7fffu + ((u >> 16) & 1u);
  return (u16)(u >> 16);
}
__device__ __forceinline__ float sigmoidf_(float x) { return 1.f / (1.f + __expf(-x)); }

__device__ __forceinline__ void async16(const void* g, void* l) {
  __builtin_amdgcn_global_load_lds((const __attribute__((address_space(1))) void*)g,
                                   (__attribute__((address_space(3))) void*)l, 16, 0, 0);
}

// ---------------- converts ----------------
__global__ __launch_bounds__(256) void cvt_x_kernel(const float* __restrict__ in, u16* __restrict__ outp) {
  const size_t i = ((size_t)blockIdx.x * 256 + threadIdx.x) * 4;
  float4 f = *(const float4*)(in + i);
  ushort4 u; u.x = f2bf(f.x); u.y = f2bf(f.y); u.z = f2bf(f.z); u.w = f2bf(f.w);
  *(ushort4*)(outp + i) = u;
}

__global__ __launch_bounds__(256) void cvt_w_kernel(const float* __restrict__ w0, const float* __restrict__ w1,
    const float* __restrict__ w2, const float* __restrict__ w3, const float* __restrict__ w4,
    u16* __restrict__ outp) {
  const int z = blockIdx.z;
  const float* src = (z == 0) ? w0 : (z == 1) ? w1 : (z == 2) ? w2 : (z == 3) ? w3 : w4;
  const size_t i = ((size_t)blockIdx.x * 256 + threadIdx.x) * 4;
  float4 f = *(const float4*)(src + i);
  ushort4 u; u.x = f2bf(f.x); u.y = f2bf(f.y); u.z = f2bf(f.z); u.w = f2bf(f.w);
  *(ushort4*)(outp + (size_t)z * (1024 * 1024) + i) = u;
}

// Wab: 32x1024 bf16; rows 0..15 = Wa, 16..31 = Wb
__global__ __launch_bounds__(256) void cvt_ab_kernel(const float* __restrict__ Wa, const float* __restrict__ Wb,
    u16* __restrict__ outp) {
  const size_t i = ((size_t)blockIdx.x * 256 + threadIdx.x) * 4;
  const int row = (int)(i >> 10);
  const float* src = (row < 16) ? (Wa + i) : (Wb + i - 16 * 1024);
  float4 f = *(const float4*)src;
  ushort4 u; u.x = f2bf(f.x); u.y = f2bf(f.y); u.z = f2bf(f.z); u.w = f2bf(f.w);
  *(ushort4*)(outp + i) = u;
}

// ---------------- alpha/beta GEMM: 8192x32 = x @ [Wa;Wb]^T, tiny, MFMA direct-from-global ----------------
__global__ __launch_bounds__(256) void ab_gemm(const u16* __restrict__ A, const u16* __restrict__ Wab,
    float* __restrict__ al, float* __restrict__ be, const float* __restrict__ ba, const float* __restrict__ bb) {
  const int tid = threadIdx.x, wv = tid >> 6, lane = tid & 63;
  const int l15 = lane & 15, qd = lane >> 4;
  const int m0 = blockIdx.x * 128 + wv * 32;
  const u16* gA = A + (size_t)m0 * 1024 + qd * 8;
  const u16* gB = Wab + (size_t)l15 * 1024 + qd * 8;
  f32x4 acc[2][2] = {};
#pragma unroll 4
  for (int kt = 0; kt < 1024; kt += 32) {
    bf16x8 a0 = *(const bf16x8*)(gA + (size_t)l15 * 1024 + kt);
    bf16x8 a1 = *(const bf16x8*)(gA + (size_t)(16 + l15) * 1024 + kt);
    bf16x8 b0 = *(const bf16x8*)(gB + kt);
    bf16x8 b1 = *(const bf16x8*)(gB + 16 * 1024 + kt);
    acc[0][0] = __builtin_amdgcn_mfma_f32_16x16x32_bf16(a0, b0, acc[0][0], 0, 0, 0);
    acc[0][1] = __builtin_amdgcn_mfma_f32_16x16x32_bf16(a0, b1, acc[0][1], 0, 0, 0);
    acc[1][0] = __builtin_amdgcn_mfma_f32_16x16x32_bf16(a1, b0, acc[1][0], 0, 0, 0);
    acc[1][1] = __builtin_amdgcn_mfma_f32_16x16x32_bf16(a1, b1, acc[1][1], 0, 0, 0);
  }
  const float bav = ba[l15], bbv = bb[l15];
#pragma unroll
  for (int mi = 0; mi < 2; ++mi) {
    const int row = m0 + mi * 16 + qd * 4;
#pragma unroll
    for (int r = 0; r < 4; ++r) {
      al[(size_t)(row + r) * 16 + l15] = sigmoidf_(acc[mi][0][r] + bav);
      be[(size_t)(row + r) * 16 + l15] = sigmoidf_(acc[mi][1][r] + bbv);
    }
  }
}

// ============ 256x256 8-phase bf16 MFMA GEMM (T1+T2+T3+T4+T5) with fused epilogues ============
__device__ __forceinline__ void lda4(bf16x8 af[4][2], const u16* LA, int wr, int mh, int l15, int qd, int l7) {
#pragma unroll
  for (int i = 0; i < 4; ++i)
#pragma unroll
    for (int kk = 0; kk < 2; ++kk)
      af[i][kk] = *(const bf16x8*)(LA + (wr * 128 + mh * 64 + i * 16 + l15) * 64 + (((kk * 4 + qd) ^ l7) * 8));
}
__device__ __forceinline__ void ldb2(bf16x8 bf[2][2], const u16* LB, int wc, int nh, int l15, int qd, int l7) {
#pragma unroll
  for (int j = 0; j < 2; ++j)
#pragma unroll
    for (int kk = 0; kk < 2; ++kk)
      bf[j][kk] = *(const bf16x8*)(LB + (wc * 64 + nh * 32 + j * 16 + l15) * 64 + (((kk * 4 + qd) ^ l7) * 8));
}
__device__ __forceinline__ void mm16(f32x4 acc[8][4], const bf16x8 af[4][2], const bf16x8 bf[2][2], int mh, int nh) {
#pragma unroll
  for (int i = 0; i < 4; ++i)
#pragma unroll
    for (int j = 0; j < 2; ++j) {
      f32x4 c = acc[mh * 4 + i][nh * 2 + j];
      c = __builtin_amdgcn_mfma_f32_16x16x32_bf16(af[i][0], bf[j][0], c, 0, 0, 0);
      c = __builtin_amdgcn_mfma_f32_16x16x32_bf16(af[i][1], bf[j][1], c, 0, 0, 0);
      acc[mh * 4 + i][nh * 2 + j] = c;
    }
}
__device__ __forceinline__ void stageH(u16* LD, int bufp, int mat, int h, const u16* gRow0, int kElem,
                                       int rr, int sl8, int wv) {
  const u16* s0 = gRow0 + (size_t)(h * 128 + rr) * 1024 + kElem + sl8;
  u16* d = LD + bufp * 32768 + mat * 16384 + h * 8192 + wv * 512;
  async16(s0, d);
  async16(s0 + (size_t)(64 * 1024), d + 4096);
}

template<int S1, int S2, int VM>
__device__ __forceinline__ void tile16(u16* LD, int bp, int kt,
    const u16* gA, const u16* gB, f32x4 acc[8][4], bf16x8 af[4][2], bf16x8 bf0[2][2], bf16x8 bf1[2][2],
    int wr, int wc, int l15, int qd, int l7, int rr, int sl8, int wv) {
  const u16* LA = LD + bp * 32768;
  const u16* LB = LA + 16384;
  // ---- ph0: quadrant (mh0, nh0); stage A-h0(t+1)
  lda4(af, LA, wr, 0, l15, qd, l7);
  ldb2(bf0, LB, wc, 0, l15, qd, l7);
  if (S1) stageH(LD, bp ^ 1, 0, 0, gA, (kt + 1) * 64, rr, sl8, wv);
  __builtin_amdgcn_s_barrier();
  asm volatile("s_waitcnt lgkmcnt(0)" ::: "memory");
  __builtin_amdgcn_sched_barrier(0);
  __builtin_amdgcn_s_setprio(1);
  mm16(acc, af, bf0, 0, 0);
  __builtin_amdgcn_s_setprio(0);
  __builtin_amdgcn_s_barrier();
  // ---- ph1: (mh0, nh1); stage A-h1(t+1)
  ldb2(bf1, LB, wc, 1, l15, qd, l7);
  if (S1) stageH(LD, bp ^ 1, 0, 1, gA, (kt + 1) * 64, rr, sl8, wv);
  __builtin_amdgcn_s_barrier();
  asm volatile("s_waitcnt lgkmcnt(0)" ::: "memory");
  __builtin_amdgcn_sched_barrier(0);
  __builtin_amdgcn_s_setprio(1);
  mm16(acc, af, bf1, 0, 1);
  __builtin_amdgcn_s_setprio(0);
  __builtin_amdgcn_s_barrier();
  // ---- ph2: (mh1, nh0); stage B-h0(t+2)
  lda4(af, LA, wr, 1, l15, qd, l7);
  if (S2) stageH(LD, bp, 1, 0, gB, (kt + 2) * 64, rr, sl8, wv);
  __builtin_amdgcn_s_barrier();
  asm volatile("s_waitcnt lgkmcnt(0)" ::: "memory");
  __builtin_amdgcn_sched_barrier(0);
  __builtin_amdgcn_s_setprio(1);
  mm16(acc, af, bf0, 1, 0);
  __builtin_amdgcn_s_setprio(0);
  __builtin_amdgcn_s_barrier();
  // ---- ph3: (mh1, nh1); stage B-h1(t+2); boundary counted-vmcnt then barrier
  if (S2) stageH(LD, bp, 1, 1, gB, (kt + 2) * 64, rr, sl8, wv);
  __builtin_amdgcn_s_barrier();
  __builtin_amdgcn_sched_barrier(0);
  __builtin_amdgcn_s_setprio(1);
  mm16(acc, af, bf1, 1, 1);
  __builtin_amdgcn_s_setprio(0);
  if (VM == 4) asm volatile("s_waitcnt vmcnt(4)" ::: "memory");
  else if (VM == 0) asm volatile("s_waitcnt vmcnt(0)" ::: "memory");
  __builtin_amdgcn_s_barrier();
}

// mode 0: plain store to Cq (final out-proj), grid 128.
// mode 1: z = q,k,v,g with fused l2norm/l2norm/silu/plain epilogues, grid 512.
__global__ __launch_bounds__(512, 2) void gemm256(const u16* __restrict__ A, const u16* __restrict__ Wall,
    float* __restrict__ Cq, float* __restrict__ Ck, float* __restrict__ Cv, float* __restrict__ Cg,
    int mode) {
  __shared__ __align__(16) u16 Lds[65536];   // 128 KiB: [buf][A|B][256][64] bf16
  u16* LD = &Lds[0];
  const int tid = threadIdx.x;
  const int wv = tid >> 6, lane = tid & 63;
  const int l15 = lane & 15, qd = lane >> 4, l7 = l15 & 7;
  const int wr = wv >> 2, wc = wv & 3;
  const int rr = tid >> 3, sl8 = ((tid & 7) ^ (rr & 7)) * 8;

  // T1 bijective XCD swizzle (grid % 8 == 0): jobs ordered (z,ny major, mx minor).
  int mx, ny, z;
  const u16* Wm;
  if (mode == 0) {
    const int job = ((blockIdx.x & 7) << 4) + (blockIdx.x >> 3);   // 128 jobs
    mx = job & 31; ny = job >> 5; z = 0; Wm = Wall;
  } else {
    const int job = ((blockIdx.x & 7) << 6) + (blockIdx.x >> 3);   // 512 jobs
    mx = job & 31; ny = (job >> 5) & 3; z = job >> 7;
    Wm = Wall + (size_t)z * (1024 * 1024);
  }
  const int m0 = mx * 256, n0 = ny * 256;
  const u16* gA = A + (size_t)m0 * 1024;
  const u16* gB = Wm + (size_t)n0 * 1024;

  f32x4 acc[8][4] = {};
  bf16x8 af[4][2], bf0[2][2], bf1[2][2];

  // prologue: tile0 all 4 halves -> buf0; tile1 B halves -> buf1; wait tile0 landed (4 loads in flight)
  stageH(LD, 0, 0, 0, gA, 0,  rr, sl8, wv);
  stageH(LD, 0, 0, 1, gA, 0,  rr, sl8, wv);
  stageH(LD, 0, 1, 0, gB, 0,  rr, sl8, wv);
  stageH(LD, 0, 1, 1, gB, 0,  rr, sl8, wv);
  stageH(LD, 1, 1, 0, gB, 64, rr, sl8, wv);
  stageH(LD, 1, 1, 1, gB, 64, rr, sl8, wv);
  asm volatile("s_waitcnt vmcnt(4)" ::: "memory");
  __builtin_amdgcn_s_barrier();

  // 16 K-tiles (K=1024, BK=64); 2 tiles per iter so buffer parity is compile-time
#pragma unroll 1
  for (int t2 = 0; t2 < 7; ++t2) {
    tile16<1, 1, 4>(LD, 0, 2 * t2,     gA, gB, acc, af, bf0, bf1, wr, wc, l15, qd, l7, rr, sl8, wv);
    tile16<1, 1, 4>(LD, 1, 2 * t2 + 1, gA, gB, acc, af, bf0, bf1, wr, wc, l15, qd, l7, rr, sl8, wv);
  }
  tile16<1, 0, 0>(LD, 0, 14, gA, gB, acc, af, bf0, bf1, wr, wc, l15, qd, l7, rr, sl8, wv);
  tile16<0, 0, -1>(LD, 1, 15, gA, gB, acc, af, bf0, bf1, wr, wc, l15, qd, l7, rr, sl8, wv);

  // ---- epilogues ---- C/D layout per 16x16 frag: col = l15, row = qd*4 + r
  if (mode == 1 && z <= 1) {
#pragma unroll
    for (int mi = 0; mi < 8; ++mi)
#pragma unroll
      for (int r = 0; r < 4; ++r) {
        float ss = acc[mi][0][r] * acc[mi][0][r] + acc[mi][1][r] * acc[mi][1][r]
                 + acc[mi][2][r] * acc[mi][2][r] + acc[mi][3][r] * acc[mi][3][r];
        ss += __shfl_xor(ss, 1); ss += __shfl_xor(ss, 2);
        ss += __shfl_xor(ss, 4); ss += __shfl_xor(ss, 8);
        const float rn = 1.f / fmaxf(sqrtf(ss), 1e-12f);
        acc[mi][0][r] *= rn; acc[mi][1][r] *= rn; acc[mi][2][r] *= rn; acc[mi][3][r] *= rn;
      }
  } else if (mode == 1 && z == 2) {
#pragma unroll
    for (int mi = 0; mi < 8; ++mi)
#pragma unroll
      for (int ni = 0; ni < 4; ++ni)
#pragma unroll
        for (int r = 0; r < 4; ++r)
          acc[mi][ni][r] = acc[mi][ni][r] * sigmoidf_(acc[mi][ni][r]);
  }
  float* C = (mode == 0) ? Cq : ((z == 0) ? Cq : (z == 1) ? Ck : (z == 2) ? Cv : Cg);
#pragma unroll
  for (int mi = 0; mi < 8; ++mi) {
    const int row = m0 + wr * 128 + mi * 16 + qd * 4;
#pragma unroll
    for (int ni = 0; ni < 4; ++ni) {
      const int col = n0 + wc * 64 + ni * 16 + l15;
#pragma unroll
      for (int r = 0; r < 4; ++r)
        C[(size_t)(row + r) * 1024 + col] = acc[mi][ni][r];
    }
  }
}

// ================= chunked scan: 1 chunk/block, 4 row-split waves (4 blocks/CU) =================
// ROUND-2 PROVEN FORM (indexed LDS loads, modest unroll). The r3/r4 hand-rotated pipeline put
// Pr/Qr/st into scratch (4 GB traffic, 10x slowdown) -- do not reintroduce rotation temporaries.
struct ScanLds1 { float kb[2][16 * 64]; float vb[2][16 * 64]; float ab[2][32]; };
struct ScanLds2 { float kb[2][16 * 64]; float qb[2][16 * 64]; float vb[2][16 * 64]; float ab[2][32]; };

// pass 1: compose affine maps over the chunk (Pr/Qr, 2x8 tile per lane)
__global__ __launch_bounds__(256, 4) void scan_p1(const float* __restrict__ k, const float* __restrict__ v,
    const float* __restrict__ al, const float* __restrict__ be,
    float* __restrict__ P, float* __restrict__ Q) {
  __shared__ ScanLds1 L;
  const int tid = threadIdx.x, wv = tid >> 6, lane = tid & 63;
  const int bh = blockIdx.x >> 4, c = blockIdx.x & 15;
  const int b = bh >> 4, h = bh & 15;
  const int rg = lane >> 3, cg = lane & 7;
  const int r0 = wv * 16 + rg * 2, c8 = cg * 8;
  const size_t base0 = ((size_t)(b * Sq + c * LCH)) * 1024 + h * 64;
  const size_t ab0   = ((size_t)(b * Sq + c * LCH)) * 16 + h;
  const int tokw = lane >> 4, seg = lane & 15;
  auto stage = [&](int tile, int bi) {
    #pragma unroll
    for (int j = 0; j < 2; ++j) {        // 8 jobs: (arr{k,v}, quarter)
      const int job = wv * 2 + j;
      const int arr = job >> 2, i = job & 3;
      const float* src = arr ? v : k;
      float* dst = arr ? &L.vb[bi][i * 256] : &L.kb[bi][i * 256];
      async16(src + base0 + (size_t)(tile * 16 + i * 4 + tokw) * 1024 + seg * 4, dst);
    }
    if (wv == 0 && lane < 32) {          // a/b: 32 values, one lane each
      const int w16 = lane >> 4, tt = lane & 15;
      const float* s = w16 ? be : al;
      L.ab[bi][w16 * 16 + tt] = s[ab0 + (size_t)(tile * 16 + tt) * 16];
    }
  };
  float Pr[16], Qr[16];
  #pragma unroll
  for (int i = 0; i < 16; ++i) { Pr[i] = 1.f; Qr[i] = 0.f; }
  stage(0, 0);
  for (int tile = 0; tile < 8; ++tile) {
    __syncthreads();
    if (tile < 7) stage(tile + 1, (tile + 1) & 1);
    const int bi = tile & 1;
    const float* kbp = L.kb[bi];
    const float* vbp = L.vb[bi];
    const float* abp = L.ab[bi];
    #pragma unroll 4
    for (int tt = 0; tt < 16; ++tt) {
      const float a = abp[tt], bt = abp[16 + tt];
      float4 kcv0 = *(const float4*)(kbp + tt * 64 + c8);
      float4 kcv1 = *(const float4*)(kbp + tt * 64 + c8 + 4);
      float2 krvv = *(const float2*)(kbp + tt * 64 + r0);
      float2 vrvv = *(const float2*)(vbp + tt * 64 + r0);
      const float kcv[8] = {kcv0.x, kcv0.y, kcv0.z, kcv0.w, kcv1.x, kcv1.y, kcv1.z, kcv1.w};
      const float krv[2] = {krvv.x, krvv.y};
      const float vrv[2] = {vrvv.x, vrvv.y};
      const float abt = a * bt;
      float c1[2], c2[2];
      #pragma unroll
      for (int i = 0; i < 2; ++i) { c1[i] = abt * krv[i]; c2[i] = bt * vrv[i]; }
      #pragma unroll
      for (int i = 0; i < 2; ++i)
        #pragma unroll
        for (int j = 0; j < 8; ++j) {
          const int e = i * 8 + j;
          const float A = fmaf(-c1[i], kcv[j], a);
          Qr[e] = fmaf(A, Qr[e], c2[i] * kcv[j]);
          Pr[e] *= A;
        }
    }
  }
  const size_t pbase = ((size_t)bh * CCH + c) * 4096 + (size_t)c8;
  #pragma unroll
  for (int i = 0; i < 2; ++i) {
    const size_t pi = pbase + (size_t)(r0 + i) * 64;
    *(float4*)(P + pi)     = make_float4(Pr[i*8],   Pr[i*8+1], Pr[i*8+2], Pr[i*8+3]);
    *(float4*)(P + pi + 4) = make_float4(Pr[i*8+4], Pr[i*8+5], Pr[i*8+6], Pr[i*8+7]);
    *(float4*)(Q + pi)     = make_float4(Qr[i*8],   Qr[i*8+1], Qr[i*8+2], Qr[i*8+3]);
    *(float4*)(Q + pi + 4) = make_float4(Qr[i*8+4], Qr[i*8+5], Qr[i*8+6], Qr[i*8+7]);
  }
}

// pass 2: sequential combine over chunks; writes chunk-initial state over P
__global__ __launch_bounds__(256) void scan_comb(float* __restrict__ P, const float* __restrict__ Q) {
  const int g = blockIdx.x * 256 + threadIdx.x;  // 0..262143
  const int elem = g & 4095;
  const int bh = g >> 12;
  float s = 0.f;
  #pragma unroll
  for (int c = 0; c < CCH; ++c) {
    const size_t idx = ((size_t)bh * CCH + c) * 4096 + elem;
    const float p = P[idx], qq = Q[idx];
    P[idx] = s;
    s = fmaf(p, s, qq);
  }
}

// pass 3: re-iterate chunk from s_init, emit outputs
__global__ __launch_bounds__(256, 4) void scan_p2(const float* __restrict__ q, const float* __restrict__ k,
    const float* __restrict__ v, const float* __restrict__ al, const float* __restrict__ be,
    const float* __restrict__ Pini, float* __restrict__ o) {
  __shared__ ScanLds2 L;
  const int tid = threadIdx.x, wv = tid >> 6, lane = tid & 63;
  const int bh = blockIdx.x >> 4, c = blockIdx.x & 15;
  const int b = bh >> 4, h = bh & 15;
  const int rg = lane >> 3, cg = lane & 7;
  const int r0 = wv * 16 + rg * 2, c8 = cg * 8;
  const size_t base0 = ((size_t)(b * Sq + c * LCH)) * 1024 + h * 64;
  const size_t ab0   = ((size_t)(b * Sq + c * LCH)) * 16 + h;
  const size_t pbase = ((size_t)bh * CCH + c) * 4096 + (size_t)c8;
  const int tokw = lane >> 4, seg = lane & 15;
  auto stage = [&](int tile, int bi) {
    #pragma unroll
    for (int j = 0; j < 3; ++j) {        // 12 jobs: (arr{k,q,v}, quarter)
      const int job = wv * 3 + j;
      const int arr = job >> 2, i = job & 3;
      const float* src = (arr == 0) ? k : (arr == 1) ? q : v;
      float* dst = (arr == 0) ? &L.kb[bi][i * 256] : (arr == 1) ? &L.qb[bi][i * 256]
                                                                : &L.vb[bi][i * 256];
      async16(src + base0 + (size_t)(tile * 16 + i * 4 + tokw) * 1024 + seg * 4, dst);
    }
    if (wv == 0 && lane < 32) {
      const int w16 = lane >> 4, tt = lane & 15;
      const float* s = w16 ? be : al;
      L.ab[bi][w16 * 16 + tt] = s[ab0 + (size_t)(tile * 16 + tt) * 16];
    }
  };
  float st[16];
  #pragma unroll
  for (int i = 0; i < 2; ++i) {
    float4 s0 = *(const float4*)(Pini + pbase + (size_t)(r0 + i) * 64);
    float4 s1 = *(const float4*)(Pini + pbase + (size_t)(r0 + i) * 64 + 4);
    st[i*8]   = s0.x; st[i*8+1] = s0.y; st[i*8+2] = s0.z; st[i*8+3] = s0.w;
    st[i*8+4] = s1.x; st[i*8+5] = s1.y; st[i*8+6] = s1.z; st[i*8+7] = s1.w;
  }
  stage(0, 0);
  const bool hi4 = (cg & 4);
  const int rowIdx = r0 + (cg >> 2);
  const bool doStore = ((cg & 3) == 0);
  for (int tile = 0; tile < 8; ++tile) {
    __syncthreads();
    if (tile < 7) stage(tile + 1, (tile + 1) & 1);
    const int bi = tile & 1;
    const float* kbp = L.kb[bi];
    const float* qbp = L.qb[bi];
    const float* vbp = L.vb[bi];
    const float* abp = L.ab[bi];
    #pragma unroll 2
    for (int tt = 0; tt < 16; ++tt) {
      const int t = tile * 16 + tt;
      const float a = abp[tt], bt = abp[16 + tt];
      float4 kc0 = *(const float4*)(kbp + tt * 64 + c8);
      float4 kc1 = *(const float4*)(kbp + tt * 64 + c8 + 4);
      float4 qc0 = *(const float4*)(qbp + tt * 64 + c8);
      float4 qc1 = *(const float4*)(qbp + tt * 64 + c8 + 4);
      float2 krvv = *(const float2*)(kbp + tt * 64 + r0);
      float2 vrvv = *(const float2*)(vbp + tt * 64 + r0);
      const float kcv[8] = {kc0.x, kc0.y, kc0.z, kc0.w, kc1.x, kc1.y, kc1.z, kc1.w};
      const float qcv[8] = {qc0.x, qc0.y, qc0.z, qc0.w, qc1.x, qc1.y, qc1.z, qc1.w};
      const float krv[2] = {krvv.x, krvv.y};
      const float vrv[2] = {vrvv.x, vrvv.y};
      const float abt = a * bt;
      float c1[2], c2[2];
      #pragma unroll
      for (int i = 0; i < 2; ++i) { c1[i] = abt * krv[i]; c2[i] = bt * vrv[i]; }
      float p[2];
      p[0] = 0.f; p[1] = 0.f;
      #pragma unroll
      for (int i = 0; i < 2; ++i)
        #pragma unroll
        for (int j = 0; j < 8; ++j) {
          const int e = i * 8 + j;
          const float A = fmaf(-c1[i], kcv[j], a);
          st[e] = fmaf(A, st[e], c2[i] * kcv[j]);
          p[i] = fmaf(st[e], qcv[j], p[i]);
        }
      // reduce over the 8 col-lanes: keep-one/send-one split at xor4, then xor2/xor1.
      // lanes cg 0..3 end with row r0's total, cg 4..7 with row r0+1's; cg 0 and 4 store.
      float my    = hi4 ? p[1] : p[0];
      float other = hi4 ? p[0] : p[1];
      my += __shfl_xor(other, 4);
      my += __shfl_xor(my, 2);
      my += __shfl_xor(my, 1);
      if (doStore) o[base0 + (size_t)t * 1024 + rowIdx] = my;
    }
  }
}

// ---------------- LayerNorm + silu-gate, write bf16 ----------------
__global__ __launch_bounds__(256) void ln_gate_kernel(const float* __restrict__ o, const float* __restrict__ g,
    const float* __restrict__ ln_g, const float* __restrict__ ln_b, u16* __restrict__ y) {
  const int t = blockIdx.x, tid = threadIdx.x;
  const size_t row = (size_t)t * 1024;
  float4 xv = *(const float4*)(o + row + tid * 4);
  float s  = xv.x + xv.y + xv.z + xv.w;
  float s2 = xv.x * xv.x + xv.y * xv.y + xv.z * xv.z + xv.w * xv.w;
  #pragma unroll
  for (int m = 1; m < 64; m <<= 1) { s += __shfl_xor(s, m); s2 += __shfl_xor(s2, m); }
  __shared__ float red[8];
  const int w = tid >> 6, lane = tid & 63;
  if (lane == 0) { red[w] = s; red[4 + w] = s2; }
  __syncthreads();
  s  = red[0] + red[1] + red[2] + red[3];
  s2 = red[4] + red[5] + red[6] + red[7];
  const float mu = s * (1.f / 1024.f);
  const float var = s2 * (1.f / 1024.f) - mu * mu;
  const float rstd = rsqrtf(var + 1e-5f);
  float4 gv = *(const float4*)(g + row + tid * 4);
  float4 lg = *(const float4*)(ln_g + tid * 4);
  float4 lb = *(const float4*)(ln_b + tid * 4);
  ushort4 u;
  u.x = f2bf(((xv.x - mu) * rstd * lg.x + lb.x) * (gv.x * sigmoidf_(gv.x)));
  u.y = f2bf(((xv.y - mu) * rstd * lg.y + lb.y) * (gv.y * sigmoidf_(gv.y)));
  u.z = f2bf(((xv.z - mu) * rstd * lg.z + lb.z) * (gv.z * sigmoidf_(gv.z)));
  u.w = f2bf(((xv.w - mu) * rstd * lg.w + lb.w) * (gv.w * sigmoidf_(gv.w)));
  *(ushort4*)(y + row + tid * 4) = u;
}

extern "C" void kernel_launch(void* const* d_in, const int* in_sizes, int n_in,
                              void* d_out, int out_size, void* d_ws, size_t ws_size,
                              hipStream_t stream) {
  const float* x    = (const float*)d_in[0];
  const float* Wq   = (const float*)d_in[1];
  const float* Wk   = (const float*)d_in[2];
  const float* Wv   = (const float*)d_in[3];
  const float* Wa   = (const float*)d_in[4];
  const float* ba   = (const float*)d_in[5];
  const float* Wb   = (const float*)d_in[6];
  const float* bb   = (const float*)d_in[7];
  const float* Wg   = (const float*)d_in[8];
  const float* Wo   = (const float*)d_in[9];
  const float* ln_g = (const float*)d_in[10];
  const float* ln_b = (const float*)d_in[11];
  float* out = (float*)d_out;
  char* ws = (char*)d_ws;

  u16*   wb  = (u16*)(ws + OFF_WB);
  u16*   xb  = (u16*)(ws + OFF_XB);   // x-bf16 -> Qc -> y-bf16
  float* qf  = (float*)(ws + OFF_Q);
  float* kf  = (float*)(ws + OFF_K);
  float* vf  = (float*)(ws + OFF_V);
  float* gf  = (float*)(ws + OFF_G);
  float* al  = (float*)(ws + OFF_AL);
  float* be  = (float*)(ws + OFF_BE);
  u16*   wab = (u16*)(ws + OFF_P);    // Wab bf16 (32x1024) during GEMM; region later becomes P
  float* Pb  = (float*)(ws + OFF_P);
  float* Qc  = (float*)(ws + OFF_XB); // reuses dead x-bf16 region
  float* of  = (float*)(ws + OFF_O);
  u16*   yb  = xb;

  cvt_x_kernel<<<8192, 256, 0, stream>>>(x, xb);
  cvt_w_kernel<<<dim3(1024, 1, 5), 256, 0, stream>>>(Wq, Wk, Wv, Wg, Wo, wb);
  cvt_ab_kernel<<<32, 256, 0, stream>>>(Wa, Wb, wab);
  // alpha/beta: tiny dedicated MFMA GEMM (64 blocks)
  ab_gemm<<<64, 256, 0, stream>>>(xb, wab, al, be, ba, bb);
  // projections q,k,v,g: 256x256 8-phase MFMA GEMM, fused epilogues; 512 blocks = 2 clean generations
  gemm256<<<512, 512, 0, stream>>>(xb, wb, qf, kf, vf, gf, 1);
  // chunked scan: 1 chunk/block, 4 row-split waves, 1024 blocks -> 4 blocks/CU
  scan_p1<<<1024, 256, 0, stream>>>(kf, vf, al, be, Pb, Qc);
  scan_comb<<<1024, 256, 0, stream>>>(Pb, Qc);
  scan_p2<<<1024, 256, 0, stream>>>(qf, kf, vf, al, be, Pb, of);
  // epilogue
  ln_gate_kernel<<<8192, 256, 0, stream>>>(of, gf, ln_g, ln_b, yb);
  gemm256<<<128, 512, 0, stream>>>(yb, wb + (size_t)4 * 1024 * 1024, out, out, out, out, 0);
}